// Round 1
// baseline (5336.663 us; speedup 1.0000x reference)
//
#include <hip/hip_runtime.h>

// ---------------------------------------------------------------------------
// Waveletnet: Haar DWT U-Net, fp32 baseline.
// wt/iwt are closed-form 2x2 Haar butterflies (affine (v+1)/2 and 2v-1 folded).
// conv3x3: direct conv, 1 thread = 1 pixel x CO output channels.
//   - weight index is block-uniform (blockIdx.y * CO + i, ci loop) -> scalar loads
//   - concat inputs handled by dual source pointers (no concat copies)
// Final stage fuses iwt + 1x1 conv.
// Workspace map (floats):
//   C1 @ 0        (4,16,128,128) = 1048576
//   C2 @ 1M       (4,64,64,64)   = 1048576
//   C3 @ 2M       (4,256,32,32)  = 1048576
//   W4 @ 3M       (4,1024,16,16) = 1048576
//   TA @ 4M       ping           <= 1048576
//   TB @ 5M       pong           <= 1048576
// total 24 MB.
// ---------------------------------------------------------------------------

#define TPB 256

__global__ __launch_bounds__(TPB) void wt_k(const float* __restrict__ src,
                                            float* __restrict__ dst,
                                            int C, int H2, int W2) {
    int n = C * H2 * W2;
    int idx = blockIdx.x * TPB + threadIdx.x;
    if (idx >= n) return;
    int b = blockIdx.z;
    int c = idx / (H2 * W2);
    int p = idx - c * (H2 * W2);
    int h = p / W2, w = p - h * W2;
    int W = 2 * W2;
    const float* r = src + (((size_t)b * C + c) * (2 * H2) + 2 * h) * W + 2 * w;
    float a = r[0], bb = r[1], cc = r[W], dd = r[W + 1];
    size_t st = (size_t)H2 * W2;
    float* o = dst + (((size_t)b * 4 * C + 4 * c) * st) + p;
    o[0]      = 0.25f * (a + bb + cc + dd);
    o[st]     = (0.5f * (a + bb - cc - dd) + 1.0f) * 0.5f;
    o[2 * st] = (0.5f * (a - bb + cc - dd) + 1.0f) * 0.5f;
    o[3 * st] = (0.5f * (a - bb - cc + dd) + 1.0f) * 0.5f;
}

// C = output channel count (= input_channels/4); H,W = input spatial dims.
__global__ __launch_bounds__(TPB) void iwt_k(const float* __restrict__ src,
                                             float* __restrict__ dst,
                                             int C, int H, int W) {
    int n = C * H * W;
    int idx = blockIdx.x * TPB + threadIdx.x;
    if (idx >= n) return;
    int b = blockIdx.z;
    int c = idx / (H * W);
    int p = idx - c * (H * W);
    int h = p / W, w = p - h * W;
    size_t st = (size_t)H * W;
    const float* r = src + ((size_t)b * 4 * C + 4 * c) * st + p;
    float v0 = r[0];
    float v1 = 2.0f * r[st] - 1.0f;
    float v2 = 2.0f * r[2 * st] - 1.0f;
    float v3 = 2.0f * r[3 * st] - 1.0f;
    float* o = dst + (((size_t)b * C + c) * (2 * H) + 2 * h) * (2 * W) + 2 * w;
    o[0]         = v0 + 0.5f * ( v1 + v2 + v3);
    o[1]         = v0 + 0.5f * ( v1 - v2 - v3);
    o[2 * W]     = v0 + 0.5f * (-v1 + v2 - v3);
    o[2 * W + 1] = v0 + 0.5f * (-v1 - v2 + v3);
}

// Direct 3x3 conv, pad=1. Input channels ci<C0 come from s0, rest from s1.
// One thread: one pixel, CO consecutive output channels starting at blockIdx.y*CO.
template <int CO, bool LRELU, bool HAS_SKIP>
__global__ __launch_bounds__(TPB) void conv3x3_k(
    const float* __restrict__ s0, int C0,
    const float* __restrict__ s1,
    const float* __restrict__ wgt, const float* __restrict__ bias,
    const float* __restrict__ skip,
    float* __restrict__ out,
    int Cin, int Cout, int H, int W) {
    const int hw = H * W;
    int p = blockIdx.x * TPB + threadIdx.x;
    if (p >= hw) return;
    const int b = blockIdx.z;
    const int cog = blockIdx.y * CO;
    const int h = p / W, w = p - (p / W) * W;
    const bool hm = h > 0, hp = h < H - 1, wm = w > 0, wpp = w < W - 1;

    float acc[CO];
#pragma unroll
    for (int i = 0; i < CO; i++) acc[i] = bias[cog + i];

    const int C1n = Cin - C0;
    for (int ci = 0; ci < Cin; ci++) {
        const float* sp = (ci < C0)
            ? s0 + ((size_t)b * C0 + ci) * hw
            : s1 + ((size_t)b * C1n + (ci - C0)) * hw;
        const float* r = sp + p;
        float x00 = (hm && wm)  ? r[-W - 1] : 0.0f;
        float x01 = hm          ? r[-W]     : 0.0f;
        float x02 = (hm && wpp) ? r[-W + 1] : 0.0f;
        float x10 = wm          ? r[-1]     : 0.0f;
        float x11 =               r[0];
        float x12 = wpp         ? r[1]      : 0.0f;
        float x20 = (hp && wm)  ? r[W - 1]  : 0.0f;
        float x21 = hp          ? r[W]      : 0.0f;
        float x22 = (hp && wpp) ? r[W + 1]  : 0.0f;
        const float* wk = wgt + ((size_t)cog * Cin + ci) * 9;
#pragma unroll
        for (int i = 0; i < CO; i++) {
            const float* wi = wk + (size_t)i * Cin * 9;
            acc[i] += x00 * wi[0] + x01 * wi[1] + x02 * wi[2]
                    + x10 * wi[3] + x11 * wi[4] + x12 * wi[5]
                    + x20 * wi[6] + x21 * wi[7] + x22 * wi[8];
        }
    }
#pragma unroll
    for (int i = 0; i < CO; i++) {
        float v = acc[i];
        if (HAS_SKIP) v += skip[((size_t)b * Cout + cog + i) * hw + p];
        if (LRELU) v = (v >= 0.0f) ? v : 0.2f * v;
        out[((size_t)b * Cout + cog + i) * hw + p] = v;
    }
}

// Fused final iwt (12ch -> 3ch, 128->256) + 1x1 conv (3->3, no bias).
__global__ __launch_bounds__(TPB) void final_k(const float* __restrict__ src,
                                               const float* __restrict__ cf,
                                               float* __restrict__ out) {
    int p = blockIdx.x * TPB + threadIdx.x;  // 0..16383 over 128x128
    int b = blockIdx.z;
    int h = p >> 7, w = p & 127;
    const int st = 128 * 128;
    float y00[3], y01[3], y10[3], y11[3];
    const float* r = src + (size_t)b * 12 * st + p;
#pragma unroll
    for (int c = 0; c < 3; c++) {
        float v0 = r[(4 * c) * st];
        float v1 = 2.0f * r[(4 * c + 1) * st] - 1.0f;
        float v2 = 2.0f * r[(4 * c + 2) * st] - 1.0f;
        float v3 = 2.0f * r[(4 * c + 3) * st] - 1.0f;
        y00[c] = v0 + 0.5f * ( v1 + v2 + v3);
        y01[c] = v0 + 0.5f * ( v1 - v2 - v3);
        y10[c] = v0 + 0.5f * (-v1 + v2 - v3);
        y11[c] = v0 + 0.5f * (-v1 - v2 + v3);
    }
#pragma unroll
    for (int o = 0; o < 3; o++) {
        float k0 = cf[o * 3], k1 = cf[o * 3 + 1], k2 = cf[o * 3 + 2];
        float* q = out + (((size_t)b * 3 + o) * 256 + 2 * h) * 256 + 2 * w;
        q[0]   = k0 * y00[0] + k1 * y00[1] + k2 * y00[2];
        q[1]   = k0 * y01[0] + k1 * y01[1] + k2 * y01[2];
        q[256] = k0 * y10[0] + k1 * y10[1] + k2 * y10[2];
        q[257] = k0 * y11[0] + k1 * y11[1] + k2 * y11[2];
    }
}

static inline void conv_launch(const float* s0, int C0, const float* s1,
                               const float* wgt, const float* bias,
                               const float* skip, float* out,
                               int Cin, int Cout, int H, int W,
                               bool has_skip, int CO, hipStream_t st) {
    dim3 grid((H * W + TPB - 1) / TPB, Cout / CO, 4);
    if (CO == 8) {
        if (has_skip)
            conv3x3_k<8, true, true><<<grid, TPB, 0, st>>>(s0, C0, s1, wgt, bias, skip, out, Cin, Cout, H, W);
        else
            conv3x3_k<8, true, false><<<grid, TPB, 0, st>>>(s0, C0, s1, wgt, bias, skip, out, Cin, Cout, H, W);
    } else {
        conv3x3_k<4, true, false><<<grid, TPB, 0, st>>>(s0, C0, s1, wgt, bias, skip, out, Cin, Cout, H, W);
    }
}

extern "C" void kernel_launch(void* const* d_in, const int* in_sizes, int n_in,
                              void* d_out, int out_size, void* d_ws, size_t ws_size,
                              hipStream_t stream) {
    (void)in_sizes; (void)n_in; (void)out_size; (void)ws_size;
    const float* x      = (const float*)d_in[0];
    const float* c1w    = (const float*)d_in[1];
    const float* c1b    = (const float*)d_in[2];
    const float* c2w    = (const float*)d_in[3];
    const float* c2b    = (const float*)d_in[4];
    const float* c3w    = (const float*)d_in[5];
    const float* c3b    = (const float*)d_in[6];
    const float* c4w    = (const float*)d_in[7];
    const float* c4b    = (const float*)d_in[8];
    const float* d4w    = (const float*)d_in[9];
    const float* d4b    = (const float*)d_in[10];
    const float* d3w    = (const float*)d_in[11];
    const float* d3b    = (const float*)d_in[12];
    const float* d2w    = (const float*)d_in[13];
    const float* d2b    = (const float*)d_in[14];
    const float* d1w    = (const float*)d_in[15];
    const float* d1b    = (const float*)d_in[16];
    const float* cfin   = (const float*)d_in[17];
    float* out = (float*)d_out;

    float* ws = (float*)d_ws;
    const size_t M = 1048576;
    float* C1 = ws;
    float* C2 = ws + 1 * M;
    float* C3 = ws + 2 * M;
    float* W4 = ws + 3 * M;
    float* TA = ws + 4 * M;
    float* TB = ws + 5 * M;

    // 1. w1 = wt(x): (4,3,256,256) -> (4,12,128,128), in TA
    wt_k<<<dim3(3 * 128 * 128 / TPB, 1, 4), TPB, 0, stream>>>(x, TA, 3, 128, 128);
    // 2. c1 = lrelu(conv1(w1)): 12 -> 16 @128^2
    conv_launch(TA, 12, nullptr, c1w, c1b, nullptr, C1, 12, 16, 128, 128, false, 8, stream);
    // 3. w2 = wt(c1): -> (4,64,64,64) in TA
    wt_k<<<dim3(16 * 64 * 64 / TPB, 1, 4), TPB, 0, stream>>>(C1, TA, 16, 64, 64);
    // 4. c2 = lrelu(conv2(w2)): 64 -> 64 @64^2
    conv_launch(TA, 64, nullptr, c2w, c2b, nullptr, C2, 64, 64, 64, 64, false, 8, stream);
    // 5. w3 = wt(c2): -> (4,256,32,32) in TA
    wt_k<<<dim3(64 * 32 * 32 / TPB, 1, 4), TPB, 0, stream>>>(C2, TA, 64, 32, 32);
    // 6. c3 = lrelu(conv3(w3)): 256 -> 256 @32^2
    conv_launch(TA, 256, nullptr, c3w, c3b, nullptr, C3, 256, 256, 32, 32, false, 8, stream);
    // 7. w4 = wt(c3): -> (4,1024,16,16) in W4 (kept for skip)
    wt_k<<<dim3(256 * 16 * 16 / TPB, 1, 4), TPB, 0, stream>>>(C3, W4, 256, 16, 16);
    // 8. c4 = lrelu(conv4(w4)) -> TA
    conv_launch(W4, 1024, nullptr, c4w, c4b, nullptr, TA, 1024, 1024, 16, 16, false, 8, stream);
    // 9. c5 = lrelu(conv4(c4)) -> TB
    conv_launch(TA, 1024, nullptr, c4w, c4b, nullptr, TB, 1024, 1024, 16, 16, false, 8, stream);
    // 10. ic4 = lrelu(conv4(c5) + w4) -> TA
    conv_launch(TB, 1024, nullptr, c4w, c4b, W4, TA, 1024, 1024, 16, 16, true, 8, stream);
    // 11. t4 = iwt(ic4): (4,1024,16,16) -> (4,256,32,32) in TB
    iwt_k<<<dim3(256 * 16 * 16 / TPB, 1, 4), TPB, 0, stream>>>(TA, TB, 256, 16, 16);
    // 12. ic3 = lrelu(convd4(c3 || t4)): 512 -> 256 @32^2 -> TA
    conv_launch(C3, 256, TB, d4w, d4b, nullptr, TA, 512, 256, 32, 32, false, 8, stream);
    // 13. t3 = iwt(ic3): -> (4,64,64,64) in TB
    iwt_k<<<dim3(64 * 32 * 32 / TPB, 1, 4), TPB, 0, stream>>>(TA, TB, 64, 32, 32);
    // 14. ic2 = lrelu(convd3(c2 || t3)): 128 -> 64 @64^2 -> TA
    conv_launch(C2, 64, TB, d3w, d3b, nullptr, TA, 128, 64, 64, 64, false, 8, stream);
    // 15. t2 = iwt(ic2): -> (4,16,128,128) in TB
    iwt_k<<<dim3(16 * 64 * 64 / TPB, 1, 4), TPB, 0, stream>>>(TA, TB, 16, 64, 64);
    // 16. ic1 = lrelu(convd2(c1 || t2)): 32 -> 16 @128^2 -> TA
    conv_launch(C1, 16, TB, d2w, d2b, nullptr, TA, 32, 16, 128, 128, false, 8, stream);
    // 17. iw1 = lrelu(convd1(ic1)): 16 -> 12 @128^2 -> TB
    conv_launch(TA, 16, TA, d1w, d1b, nullptr, TB, 16, 12, 128, 128, false, 4, stream);
    // 18. out = 1x1(iwt(iw1)) fused
    final_k<<<dim3(128 * 128 / TPB, 1, 4), TPB, 0, stream>>>(TB, cfin, out);
}

// Round 2
// 3231.569 us; speedup vs baseline: 1.6514x; 1.6514x over previous
//
#include <hip/hip_runtime.h>

// ---------------------------------------------------------------------------
// Waveletnet: Haar DWT U-Net, fp32.
// R1: three conv4 layers (1024->1024 @16x16) rewritten as tiled K-split
// kernel: 4px x 8co per thread (32 accs), 4-way ci split, unsafeAtomicAdd
// into bias-initialized accumulator, finalize applies (skip+)lrelu.
// Other layers unchanged from R0 baseline.
// Workspace map (floats):
//   C1 @ 0   (4,16,128,128)  C2 @ 1M  (4,64,64,64)  C3 @ 2M (4,256,32,32)
//   W4 @ 3M  (4,1024,16,16)  TA @ 4M  ping          TB @ 5M pong
// total 24 MB.
// ---------------------------------------------------------------------------

#define TPB 256
#define CONV4_KS 4

__global__ __launch_bounds__(TPB) void wt_k(const float* __restrict__ src,
                                            float* __restrict__ dst,
                                            int C, int H2, int W2) {
    int n = C * H2 * W2;
    int idx = blockIdx.x * TPB + threadIdx.x;
    if (idx >= n) return;
    int b = blockIdx.z;
    int c = idx / (H2 * W2);
    int p = idx - c * (H2 * W2);
    int h = p / W2, w = p - h * W2;
    int W = 2 * W2;
    const float* r = src + (((size_t)b * C + c) * (2 * H2) + 2 * h) * W + 2 * w;
    float a = r[0], bb = r[1], cc = r[W], dd = r[W + 1];
    size_t st = (size_t)H2 * W2;
    float* o = dst + (((size_t)b * 4 * C + 4 * c) * st) + p;
    o[0]      = 0.25f * (a + bb + cc + dd);
    o[st]     = (0.5f * (a + bb - cc - dd) + 1.0f) * 0.5f;
    o[2 * st] = (0.5f * (a - bb + cc - dd) + 1.0f) * 0.5f;
    o[3 * st] = (0.5f * (a - bb - cc + dd) + 1.0f) * 0.5f;
}

__global__ __launch_bounds__(TPB) void iwt_k(const float* __restrict__ src,
                                             float* __restrict__ dst,
                                             int C, int H, int W) {
    int n = C * H * W;
    int idx = blockIdx.x * TPB + threadIdx.x;
    if (idx >= n) return;
    int b = blockIdx.z;
    int c = idx / (H * W);
    int p = idx - c * (H * W);
    int h = p / W, w = p - h * W;
    size_t st = (size_t)H * W;
    const float* r = src + ((size_t)b * 4 * C + 4 * c) * st + p;
    float v0 = r[0];
    float v1 = 2.0f * r[st] - 1.0f;
    float v2 = 2.0f * r[2 * st] - 1.0f;
    float v3 = 2.0f * r[3 * st] - 1.0f;
    float* o = dst + (((size_t)b * C + c) * (2 * H) + 2 * h) * (2 * W) + 2 * w;
    o[0]         = v0 + 0.5f * ( v1 + v2 + v3);
    o[1]         = v0 + 0.5f * ( v1 - v2 - v3);
    o[2 * W]     = v0 + 0.5f * (-v1 + v2 - v3);
    o[2 * W + 1] = v0 + 0.5f * (-v1 - v2 + v3);
}

// Generic direct 3x3 conv (R0 version) — used for all non-conv4 layers.
template <int CO, bool LRELU, bool HAS_SKIP>
__global__ __launch_bounds__(TPB) void conv3x3_k(
    const float* __restrict__ s0, int C0,
    const float* __restrict__ s1,
    const float* __restrict__ wgt, const float* __restrict__ bias,
    const float* __restrict__ skip,
    float* __restrict__ out,
    int Cin, int Cout, int H, int W) {
    const int hw = H * W;
    int p = blockIdx.x * TPB + threadIdx.x;
    if (p >= hw) return;
    const int b = blockIdx.z;
    const int cog = blockIdx.y * CO;
    const int h = p / W, w = p - (p / W) * W;
    const bool hm = h > 0, hp = h < H - 1, wm = w > 0, wpp = w < W - 1;

    float acc[CO];
#pragma unroll
    for (int i = 0; i < CO; i++) acc[i] = bias[cog + i];

    const int C1n = Cin - C0;
    for (int ci = 0; ci < Cin; ci++) {
        const float* sp = (ci < C0)
            ? s0 + ((size_t)b * C0 + ci) * hw
            : s1 + ((size_t)b * C1n + (ci - C0)) * hw;
        const float* r = sp + p;
        float x00 = (hm && wm)  ? r[-W - 1] : 0.0f;
        float x01 = hm          ? r[-W]     : 0.0f;
        float x02 = (hm && wpp) ? r[-W + 1] : 0.0f;
        float x10 = wm          ? r[-1]     : 0.0f;
        float x11 =               r[0];
        float x12 = wpp         ? r[1]      : 0.0f;
        float x20 = (hp && wm)  ? r[W - 1]  : 0.0f;
        float x21 = hp          ? r[W]      : 0.0f;
        float x22 = (hp && wpp) ? r[W + 1]  : 0.0f;
        const float* wk = wgt + ((size_t)cog * Cin + ci) * 9;
#pragma unroll
        for (int i = 0; i < CO; i++) {
            const float* wi = wk + (size_t)i * Cin * 9;
            acc[i] += x00 * wi[0] + x01 * wi[1] + x02 * wi[2]
                    + x10 * wi[3] + x11 * wi[4] + x12 * wi[5]
                    + x20 * wi[6] + x21 * wi[7] + x22 * wi[8];
        }
    }
#pragma unroll
    for (int i = 0; i < CO; i++) {
        float v = acc[i];
        if (HAS_SKIP) v += skip[((size_t)b * Cout + cog + i) * hw + p];
        if (LRELU) v = (v >= 0.0f) ? v : 0.2f * v;
        out[((size_t)b * Cout + cog + i) * hw + p] = v;
    }
}

// ---- conv4 specialized path (Cin=Cout=1024, H=W=16, B=4) -------------------

__global__ __launch_bounds__(TPB) void bias_init_k(float* __restrict__ out,
                                                   const float* __restrict__ bias) {
    int idx = blockIdx.x * TPB + threadIdx.x;      // over 1024*256
    int b = blockIdx.z;
    int c = idx >> 8;
    out[((size_t)b * 1024 + c) * 256 + (idx & 255)] = bias[c];
}

template <bool HAS_SKIP>
__global__ __launch_bounds__(TPB) void fin_k(float* __restrict__ buf,
                                             const float* __restrict__ skip) {
    size_t i = (size_t)blockIdx.x * TPB + threadIdx.x + (size_t)blockIdx.z * (1024 * 256);
    float v = buf[i];
    if (HAS_SKIP) v += skip[i];
    buf[i] = (v >= 0.0f) ? v : 0.2f * v;
}

// Thread: batch b = tid>>6; within image: 4 adjacent pixels (row h, cols wq..wq+3)
// x 8 output channels. blockIdx.x = co-group (128), blockIdx.y = ci chunk (KS).
__global__ __launch_bounds__(TPB) void conv4_tile_k(
    const float* __restrict__ in,   // [4,1024,16,16]
    const float* __restrict__ wgt,  // [1024,1024,3,3]
    float* __restrict__ acc_out) {  // [4,1024,16,16], pre-init with bias
    const int tid = threadIdx.x;
    const int b = tid >> 6;
    const int t = tid & 63;
    const int h = t >> 2;
    const int wq = (t & 3) << 2;
    const int cog = blockIdx.x << 3;
    const int ci0 = blockIdx.y * (1024 / CONV4_KS);

    // branchless borders: clamp offsets to safe in-bounds addresses, zero by mask
    const int off0 = (h > 0) ? -16 : 0;
    const int off2 = (h < 15) ? 16 : 0;
    const int offL = (wq > 0) ? -1 : 0;
    const int offR = (wq < 12) ? 4 : 3;
    const float m0 = (h > 0) ? 1.0f : 0.0f;
    const float m2 = (h < 15) ? 1.0f : 0.0f;
    const float mL = (wq > 0) ? 1.0f : 0.0f;
    const float mR = (wq < 12) ? 1.0f : 0.0f;
    const float m0L = m0 * mL, m0R = m0 * mR, m2L = m2 * mL, m2R = m2 * mR;

    float acc[4][8];
#pragma unroll
    for (int j = 0; j < 4; j++)
#pragma unroll
        for (int i = 0; i < 8; i++) acc[j][i] = 0.0f;

    const float* p0 = in + ((size_t)b * 1024 + ci0) * 256 + h * 16 + wq;

#pragma unroll 2
    for (int c = 0; c < 1024 / CONV4_KS; ++c) {
        const float* p = p0 + (size_t)c * 256;
        float4 va = *(const float4*)(p + off0);
        float4 vb = *(const float4*)(p);
        float4 vc = *(const float4*)(p + off2);
        float l0 = p[off0 + offL], r0 = p[off0 + offR];
        float l1 = p[offL],        r1 = p[offR];
        float l2 = p[off2 + offL], r2 = p[off2 + offR];
        float x[3][6];
        x[0][0] = m0L * l0; x[0][1] = m0 * va.x; x[0][2] = m0 * va.y;
        x[0][3] = m0 * va.z; x[0][4] = m0 * va.w; x[0][5] = m0R * r0;
        x[1][0] = mL * l1;  x[1][1] = vb.x; x[1][2] = vb.y;
        x[1][3] = vb.z;     x[1][4] = vb.w; x[1][5] = mR * r1;
        x[2][0] = m2L * l2; x[2][1] = m2 * vc.x; x[2][2] = m2 * vc.y;
        x[2][3] = m2 * vc.z; x[2][4] = m2 * vc.w; x[2][5] = m2R * r2;

        const int ci = ci0 + c;
#pragma unroll
        for (int i = 0; i < 8; i++) {
            const float* wi = wgt + ((size_t)(cog + i) * 1024 + ci) * 9;
            float w00 = wi[0], w01 = wi[1], w02 = wi[2];
            float w10 = wi[3], w11 = wi[4], w12 = wi[5];
            float w20 = wi[6], w21 = wi[7], w22 = wi[8];
#pragma unroll
            for (int j = 0; j < 4; j++) {
                acc[j][i] += x[0][j] * w00 + x[0][j + 1] * w01 + x[0][j + 2] * w02
                           + x[1][j] * w10 + x[1][j + 1] * w11 + x[1][j + 2] * w12
                           + x[2][j] * w20 + x[2][j + 1] * w21 + x[2][j + 2] * w22;
            }
        }
    }

    float* o = acc_out + ((size_t)b * 1024 + cog) * 256 + h * 16 + wq;
#pragma unroll
    for (int i = 0; i < 8; i++)
#pragma unroll
        for (int j = 0; j < 4; j++)
            unsafeAtomicAdd(o + i * 256 + j, acc[j][i]);
}

// Fused final iwt (12ch -> 3ch, 128->256) + 1x1 conv (3->3, no bias).
__global__ __launch_bounds__(TPB) void final_k(const float* __restrict__ src,
                                               const float* __restrict__ cf,
                                               float* __restrict__ out) {
    int p = blockIdx.x * TPB + threadIdx.x;  // 0..16383 over 128x128
    int b = blockIdx.z;
    int h = p >> 7, w = p & 127;
    const int st = 128 * 128;
    float y00[3], y01[3], y10[3], y11[3];
    const float* r = src + (size_t)b * 12 * st + p;
#pragma unroll
    for (int c = 0; c < 3; c++) {
        float v0 = r[(4 * c) * st];
        float v1 = 2.0f * r[(4 * c + 1) * st] - 1.0f;
        float v2 = 2.0f * r[(4 * c + 2) * st] - 1.0f;
        float v3 = 2.0f * r[(4 * c + 3) * st] - 1.0f;
        y00[c] = v0 + 0.5f * ( v1 + v2 + v3);
        y01[c] = v0 + 0.5f * ( v1 - v2 - v3);
        y10[c] = v0 + 0.5f * (-v1 + v2 - v3);
        y11[c] = v0 + 0.5f * (-v1 - v2 + v3);
    }
#pragma unroll
    for (int o = 0; o < 3; o++) {
        float k0 = cf[o * 3], k1 = cf[o * 3 + 1], k2 = cf[o * 3 + 2];
        float* q = out + (((size_t)b * 3 + o) * 256 + 2 * h) * 256 + 2 * w;
        q[0]   = k0 * y00[0] + k1 * y00[1] + k2 * y00[2];
        q[1]   = k0 * y01[0] + k1 * y01[1] + k2 * y01[2];
        q[256] = k0 * y10[0] + k1 * y10[1] + k2 * y10[2];
        q[257] = k0 * y11[0] + k1 * y11[1] + k2 * y11[2];
    }
}

static inline void conv_launch(const float* s0, int C0, const float* s1,
                               const float* wgt, const float* bias,
                               const float* skip, float* out,
                               int Cin, int Cout, int H, int W,
                               bool has_skip, int CO, hipStream_t st) {
    dim3 grid((H * W + TPB - 1) / TPB, Cout / CO, 4);
    if (CO == 8) {
        if (has_skip)
            conv3x3_k<8, true, true><<<grid, TPB, 0, st>>>(s0, C0, s1, wgt, bias, skip, out, Cin, Cout, H, W);
        else
            conv3x3_k<8, true, false><<<grid, TPB, 0, st>>>(s0, C0, s1, wgt, bias, skip, out, Cin, Cout, H, W);
    } else {
        conv3x3_k<4, true, false><<<grid, TPB, 0, st>>>(s0, C0, s1, wgt, bias, skip, out, Cin, Cout, H, W);
    }
}

extern "C" void kernel_launch(void* const* d_in, const int* in_sizes, int n_in,
                              void* d_out, int out_size, void* d_ws, size_t ws_size,
                              hipStream_t stream) {
    (void)in_sizes; (void)n_in; (void)out_size; (void)ws_size;
    const float* x      = (const float*)d_in[0];
    const float* c1w    = (const float*)d_in[1];
    const float* c1b    = (const float*)d_in[2];
    const float* c2w    = (const float*)d_in[3];
    const float* c2b    = (const float*)d_in[4];
    const float* c3w    = (const float*)d_in[5];
    const float* c3b    = (const float*)d_in[6];
    const float* c4w    = (const float*)d_in[7];
    const float* c4b    = (const float*)d_in[8];
    const float* d4w    = (const float*)d_in[9];
    const float* d4b    = (const float*)d_in[10];
    const float* d3w    = (const float*)d_in[11];
    const float* d3b    = (const float*)d_in[12];
    const float* d2w    = (const float*)d_in[13];
    const float* d2b    = (const float*)d_in[14];
    const float* d1w    = (const float*)d_in[15];
    const float* d1b    = (const float*)d_in[16];
    const float* cfin   = (const float*)d_in[17];
    float* out = (float*)d_out;

    float* ws = (float*)d_ws;
    const size_t M = 1048576;
    float* C1 = ws;
    float* C2 = ws + 1 * M;
    float* C3 = ws + 2 * M;
    float* W4 = ws + 3 * M;
    float* TA = ws + 4 * M;
    float* TB = ws + 5 * M;

    const dim3 g4(128, CONV4_KS, 1);
    const dim3 gE(1024, 1, 4);  // elementwise over (4,1024,16,16)

    // 1. w1 = wt(x): (4,3,256,256) -> (4,12,128,128), in TA
    wt_k<<<dim3(3 * 128 * 128 / TPB, 1, 4), TPB, 0, stream>>>(x, TA, 3, 128, 128);
    // 2. c1 = lrelu(conv1(w1)): 12 -> 16 @128^2
    conv_launch(TA, 12, nullptr, c1w, c1b, nullptr, C1, 12, 16, 128, 128, false, 8, stream);
    // 3. w2 = wt(c1): -> (4,64,64,64) in TA
    wt_k<<<dim3(16 * 64 * 64 / TPB, 1, 4), TPB, 0, stream>>>(C1, TA, 16, 64, 64);
    // 4. c2 = lrelu(conv2(w2)): 64 -> 64 @64^2
    conv_launch(TA, 64, nullptr, c2w, c2b, nullptr, C2, 64, 64, 64, 64, false, 8, stream);
    // 5. w3 = wt(c2): -> (4,256,32,32) in TA
    wt_k<<<dim3(64 * 32 * 32 / TPB, 1, 4), TPB, 0, stream>>>(C2, TA, 64, 32, 32);
    // 6. c3 = lrelu(conv3(w3)): 256 -> 256 @32^2
    conv_launch(TA, 256, nullptr, c3w, c3b, nullptr, C3, 256, 256, 32, 32, false, 8, stream);
    // 7. w4 = wt(c3): -> (4,1024,16,16) in W4 (kept for skip)
    wt_k<<<dim3(256 * 16 * 16 / TPB, 1, 4), TPB, 0, stream>>>(C3, W4, 256, 16, 16);
    // 8. c4 = lrelu(conv4(w4)) -> TA
    bias_init_k<<<gE, TPB, 0, stream>>>(TA, c4b);
    conv4_tile_k<<<g4, TPB, 0, stream>>>(W4, c4w, TA);
    fin_k<false><<<gE, TPB, 0, stream>>>(TA, nullptr);
    // 9. c5 = lrelu(conv4(c4)) -> TB
    bias_init_k<<<gE, TPB, 0, stream>>>(TB, c4b);
    conv4_tile_k<<<g4, TPB, 0, stream>>>(TA, c4w, TB);
    fin_k<false><<<gE, TPB, 0, stream>>>(TB, nullptr);
    // 10. ic4 = lrelu(conv4(c5) + w4) -> TA
    bias_init_k<<<gE, TPB, 0, stream>>>(TA, c4b);
    conv4_tile_k<<<g4, TPB, 0, stream>>>(TB, c4w, TA);
    fin_k<true><<<gE, TPB, 0, stream>>>(TA, W4);
    // 11. t4 = iwt(ic4): (4,1024,16,16) -> (4,256,32,32) in TB
    iwt_k<<<dim3(256 * 16 * 16 / TPB, 1, 4), TPB, 0, stream>>>(TA, TB, 256, 16, 16);
    // 12. ic3 = lrelu(convd4(c3 || t4)): 512 -> 256 @32^2 -> TA
    conv_launch(C3, 256, TB, d4w, d4b, nullptr, TA, 512, 256, 32, 32, false, 8, stream);
    // 13. t3 = iwt(ic3): -> (4,64,64,64) in TB
    iwt_k<<<dim3(64 * 32 * 32 / TPB, 1, 4), TPB, 0, stream>>>(TA, TB, 64, 32, 32);
    // 14. ic2 = lrelu(convd3(c2 || t3)): 128 -> 64 @64^2 -> TA
    conv_launch(C2, 64, TB, d3w, d3b, nullptr, TA, 128, 64, 64, 64, false, 8, stream);
    // 15. t2 = iwt(ic2): -> (4,16,128,128) in TB
    iwt_k<<<dim3(16 * 64 * 64 / TPB, 1, 4), TPB, 0, stream>>>(TA, TB, 16, 64, 64);
    // 16. ic1 = lrelu(convd2(c1 || t2)): 32 -> 16 @128^2 -> TA
    conv_launch(C1, 16, TB, d2w, d2b, nullptr, TA, 32, 16, 128, 128, false, 8, stream);
    // 17. iw1 = lrelu(convd1(ic1)): 16 -> 12 @128^2 -> TB
    conv_launch(TA, 16, TA, d1w, d1b, nullptr, TB, 16, 12, 128, 128, false, 4, stream);
    // 18. out = 1x1(iwt(iw1)) fused
    final_k<<<dim3(128 * 128 / TPB, 1, 4), TPB, 0, stream>>>(TB, cfin, out);
}

// Round 3
// 2119.633 us; speedup vs baseline: 2.5177x; 1.5246x over previous
//
#include <hip/hip_runtime.h>

// ---------------------------------------------------------------------------
// Waveletnet: Haar DWT U-Net, fp32.
// R2: generalize R1's tiled K-split conv (4px x 8co per thread, branchless
// borders, unsafeAtomicAdd into bias-initialized accumulator) to conv2,
// conv3, convd4, convd3 via template convt_k<W, ROWS, CI_CHUNK>. Concat
// inputs resolved per ci-chunk (chunks never straddle the boundary).
// conv4 K-split raised 4->8 (1024 WGs, 4 waves/SIMD).
// Small layers (conv1, convd2, convd1) remain on the generic kernel.
// Workspace map (floats):
//   C1 @ 0   (4,16,128,128)  C2 @ 1M  (4,64,64,64)  C3 @ 2M (4,256,32,32)
//   W4 @ 3M  (4,1024,16,16)  TA @ 4M  ping          TB @ 5M pong
// ---------------------------------------------------------------------------

#define TPB 256
#define CONV4_KS 8

__global__ __launch_bounds__(TPB) void wt_k(const float* __restrict__ src,
                                            float* __restrict__ dst,
                                            int C, int H2, int W2) {
    int n = C * H2 * W2;
    int idx = blockIdx.x * TPB + threadIdx.x;
    if (idx >= n) return;
    int b = blockIdx.z;
    int c = idx / (H2 * W2);
    int p = idx - c * (H2 * W2);
    int h = p / W2, w = p - h * W2;
    int W = 2 * W2;
    const float* r = src + (((size_t)b * C + c) * (2 * H2) + 2 * h) * W + 2 * w;
    float a = r[0], bb = r[1], cc = r[W], dd = r[W + 1];
    size_t st = (size_t)H2 * W2;
    float* o = dst + (((size_t)b * 4 * C + 4 * c) * st) + p;
    o[0]      = 0.25f * (a + bb + cc + dd);
    o[st]     = (0.5f * (a + bb - cc - dd) + 1.0f) * 0.5f;
    o[2 * st] = (0.5f * (a - bb + cc - dd) + 1.0f) * 0.5f;
    o[3 * st] = (0.5f * (a - bb - cc + dd) + 1.0f) * 0.5f;
}

__global__ __launch_bounds__(TPB) void iwt_k(const float* __restrict__ src,
                                             float* __restrict__ dst,
                                             int C, int H, int W) {
    int n = C * H * W;
    int idx = blockIdx.x * TPB + threadIdx.x;
    if (idx >= n) return;
    int b = blockIdx.z;
    int c = idx / (H * W);
    int p = idx - c * (H * W);
    int h = p / W, w = p - h * W;
    size_t st = (size_t)H * W;
    const float* r = src + ((size_t)b * 4 * C + 4 * c) * st + p;
    float v0 = r[0];
    float v1 = 2.0f * r[st] - 1.0f;
    float v2 = 2.0f * r[2 * st] - 1.0f;
    float v3 = 2.0f * r[3 * st] - 1.0f;
    float* o = dst + (((size_t)b * C + c) * (2 * H) + 2 * h) * (2 * W) + 2 * w;
    o[0]         = v0 + 0.5f * ( v1 + v2 + v3);
    o[1]         = v0 + 0.5f * ( v1 - v2 - v3);
    o[2 * W]     = v0 + 0.5f * (-v1 + v2 - v3);
    o[2 * W + 1] = v0 + 0.5f * (-v1 - v2 + v3);
}

// Generic direct 3x3 conv — used for conv1, convd2, convd1 only.
template <int CO, bool LRELU, bool HAS_SKIP>
__global__ __launch_bounds__(TPB) void conv3x3_k(
    const float* __restrict__ s0, int C0,
    const float* __restrict__ s1,
    const float* __restrict__ wgt, const float* __restrict__ bias,
    const float* __restrict__ skip,
    float* __restrict__ out,
    int Cin, int Cout, int H, int W) {
    const int hw = H * W;
    int p = blockIdx.x * TPB + threadIdx.x;
    if (p >= hw) return;
    const int b = blockIdx.z;
    const int cog = blockIdx.y * CO;
    const int h = p / W, w = p - (p / W) * W;
    const bool hm = h > 0, hp = h < H - 1, wm = w > 0, wpp = w < W - 1;

    float acc[CO];
#pragma unroll
    for (int i = 0; i < CO; i++) acc[i] = bias[cog + i];

    const int C1n = Cin - C0;
    for (int ci = 0; ci < Cin; ci++) {
        const float* sp = (ci < C0)
            ? s0 + ((size_t)b * C0 + ci) * hw
            : s1 + ((size_t)b * C1n + (ci - C0)) * hw;
        const float* r = sp + p;
        float x00 = (hm && wm)  ? r[-W - 1] : 0.0f;
        float x01 = hm          ? r[-W]     : 0.0f;
        float x02 = (hm && wpp) ? r[-W + 1] : 0.0f;
        float x10 = wm          ? r[-1]     : 0.0f;
        float x11 =               r[0];
        float x12 = wpp         ? r[1]      : 0.0f;
        float x20 = (hp && wm)  ? r[W - 1]  : 0.0f;
        float x21 = hp          ? r[W]      : 0.0f;
        float x22 = (hp && wpp) ? r[W + 1]  : 0.0f;
        const float* wk = wgt + ((size_t)cog * Cin + ci) * 9;
#pragma unroll
        for (int i = 0; i < CO; i++) {
            const float* wi = wk + (size_t)i * Cin * 9;
            acc[i] += x00 * wi[0] + x01 * wi[1] + x02 * wi[2]
                    + x10 * wi[3] + x11 * wi[4] + x12 * wi[5]
                    + x20 * wi[6] + x21 * wi[7] + x22 * wi[8];
        }
    }
#pragma unroll
    for (int i = 0; i < CO; i++) {
        float v = acc[i];
        if (HAS_SKIP) v += skip[((size_t)b * Cout + cog + i) * hw + p];
        if (LRELU) v = (v >= 0.0f) ? v : 0.2f * v;
        out[((size_t)b * Cout + cog + i) * hw + p] = v;
    }
}

// ---- helpers for K-split conv path ----------------------------------------

__global__ __launch_bounds__(TPB) void bias_init_k(float* __restrict__ out,
                                                   const float* __restrict__ bias,
                                                   int C, int HW) {
    int idx = blockIdx.x * TPB + threadIdx.x;   // over C*HW
    int b = blockIdx.z;
    int c = idx / HW;
    out[((size_t)b * C + c) * HW + (idx - c * HW)] = bias[c];
}

template <bool HAS_SKIP>
__global__ __launch_bounds__(TPB) void fin_k(float* __restrict__ buf,
                                             const float* __restrict__ skip,
                                             int n) {
    size_t i = (size_t)blockIdx.x * TPB + threadIdx.x + (size_t)blockIdx.z * n;
    float v = buf[i];
    if (HAS_SKIP) v += skip[i];
    buf[i] = (v >= 0.0f) ? v : 0.2f * v;
}

// ---- conv4 specialized (Cin=Cout=1024, H=W=16, batch folded into block) ----
__global__ __launch_bounds__(TPB) void conv4_tile_k(
    const float* __restrict__ in,   // [4,1024,16,16]
    const float* __restrict__ wgt,  // [1024,1024,3,3]
    float* __restrict__ acc_out) {  // [4,1024,16,16], pre-init with bias
    const int tid = threadIdx.x;
    const int b = tid >> 6;
    const int t = tid & 63;
    const int h = t >> 2;
    const int wq = (t & 3) << 2;
    const int cog = blockIdx.x << 3;
    const int ci0 = blockIdx.y * (1024 / CONV4_KS);

    const int off0 = (h > 0) ? -16 : 0;
    const int off2 = (h < 15) ? 16 : 0;
    const int offL = (wq > 0) ? -1 : 0;
    const int offR = (wq < 12) ? 4 : 3;
    const float m0 = (h > 0) ? 1.0f : 0.0f;
    const float m2 = (h < 15) ? 1.0f : 0.0f;
    const float mL = (wq > 0) ? 1.0f : 0.0f;
    const float mR = (wq < 12) ? 1.0f : 0.0f;
    const float m0L = m0 * mL, m0R = m0 * mR, m2L = m2 * mL, m2R = m2 * mR;

    float acc[4][8];
#pragma unroll
    for (int j = 0; j < 4; j++)
#pragma unroll
        for (int i = 0; i < 8; i++) acc[j][i] = 0.0f;

    const float* p0 = in + ((size_t)b * 1024 + ci0) * 256 + h * 16 + wq;

#pragma unroll 2
    for (int c = 0; c < 1024 / CONV4_KS; ++c) {
        const float* p = p0 + (size_t)c * 256;
        float4 va = *(const float4*)(p + off0);
        float4 vb = *(const float4*)(p);
        float4 vc = *(const float4*)(p + off2);
        float l0 = p[off0 + offL], r0 = p[off0 + offR];
        float l1 = p[offL],        r1 = p[offR];
        float l2 = p[off2 + offL], r2 = p[off2 + offR];
        float x[3][6];
        x[0][0] = m0L * l0; x[0][1] = m0 * va.x; x[0][2] = m0 * va.y;
        x[0][3] = m0 * va.z; x[0][4] = m0 * va.w; x[0][5] = m0R * r0;
        x[1][0] = mL * l1;  x[1][1] = vb.x; x[1][2] = vb.y;
        x[1][3] = vb.z;     x[1][4] = vb.w; x[1][5] = mR * r1;
        x[2][0] = m2L * l2; x[2][1] = m2 * vc.x; x[2][2] = m2 * vc.y;
        x[2][3] = m2 * vc.z; x[2][4] = m2 * vc.w; x[2][5] = m2R * r2;

        const int ci = ci0 + c;
#pragma unroll
        for (int i = 0; i < 8; i++) {
            const float* wi = wgt + ((size_t)(cog + i) * 1024 + ci) * 9;
            float w00 = wi[0], w01 = wi[1], w02 = wi[2];
            float w10 = wi[3], w11 = wi[4], w12 = wi[5];
            float w20 = wi[6], w21 = wi[7], w22 = wi[8];
#pragma unroll
            for (int j = 0; j < 4; j++) {
                acc[j][i] += x[0][j] * w00 + x[0][j + 1] * w01 + x[0][j + 2] * w02
                           + x[1][j] * w10 + x[1][j + 1] * w11 + x[1][j + 2] * w12
                           + x[2][j] * w20 + x[2][j + 1] * w21 + x[2][j + 2] * w22;
            }
        }
    }

    float* o = acc_out + ((size_t)b * 1024 + cog) * 256 + h * 16 + wq;
#pragma unroll
    for (int i = 0; i < 8; i++)
#pragma unroll
        for (int j = 0; j < 4; j++)
            unsafeAtomicAdd(o + i * 256 + j, acc[j][i]);
}

// ---- generalized tiled K-split conv ---------------------------------------
// Square images H=W. Thread: row h, 4 cols (wq..wq+3), 8 output channels.
// ROWS rows per block (ROWS * W/4 == 256). blockIdx.x = co-group,
// blockIdx.y = ci chunk, blockIdx.z = b * (W/ROWS) + rowtile.
// Source: ci chunk < C0 reads s0, else s1 (chunks never straddle C0).
template <int W, int ROWS, int CI_CHUNK>
__global__ __launch_bounds__(TPB) void convt_k(
    const float* __restrict__ s0, int C0,
    const float* __restrict__ s1, int Cin,
    const float* __restrict__ wgt,
    float* __restrict__ acc_out, int Cout) {
    const int HW = W * W;
    const int QPR = W / 4;
    const int RT = W / ROWS;
    const int t = threadIdx.x;
    const int z = blockIdx.z;
    const int b = z / RT;
    const int rt = z - b * RT;
    const int h = rt * ROWS + t / QPR;
    const int wq = (t - (t / QPR) * QPR) * 4;
    const int cog = blockIdx.x << 3;
    const int ci0 = blockIdx.y * CI_CHUNK;

    const float* src = (ci0 < C0)
        ? s0 + ((size_t)b * C0 + ci0) * HW
        : s1 + ((size_t)b * (Cin - C0) + (ci0 - C0)) * HW;

    const int off0 = (h > 0) ? -W : 0;
    const int off2 = (h < W - 1) ? W : 0;
    const int offL = (wq > 0) ? -1 : 0;
    const int offR = (wq < W - 4) ? 4 : 3;
    const float m0 = (h > 0) ? 1.0f : 0.0f;
    const float m2 = (h < W - 1) ? 1.0f : 0.0f;
    const float mL = (wq > 0) ? 1.0f : 0.0f;
    const float mR = (wq < W - 4) ? 1.0f : 0.0f;
    const float m0L = m0 * mL, m0R = m0 * mR, m2L = m2 * mL, m2R = m2 * mR;

    float acc[4][8];
#pragma unroll
    for (int j = 0; j < 4; j++)
#pragma unroll
        for (int i = 0; i < 8; i++) acc[j][i] = 0.0f;

    const float* p0 = src + h * W + wq;

#pragma unroll 2
    for (int c = 0; c < CI_CHUNK; ++c) {
        const float* p = p0 + (size_t)c * HW;
        float4 va = *(const float4*)(p + off0);
        float4 vb = *(const float4*)(p);
        float4 vc = *(const float4*)(p + off2);
        float l0 = p[off0 + offL], r0 = p[off0 + offR];
        float l1 = p[offL],        r1 = p[offR];
        float l2 = p[off2 + offL], r2 = p[off2 + offR];
        float x[3][6];
        x[0][0] = m0L * l0; x[0][1] = m0 * va.x; x[0][2] = m0 * va.y;
        x[0][3] = m0 * va.z; x[0][4] = m0 * va.w; x[0][5] = m0R * r0;
        x[1][0] = mL * l1;  x[1][1] = vb.x; x[1][2] = vb.y;
        x[1][3] = vb.z;     x[1][4] = vb.w; x[1][5] = mR * r1;
        x[2][0] = m2L * l2; x[2][1] = m2 * vc.x; x[2][2] = m2 * vc.y;
        x[2][3] = m2 * vc.z; x[2][4] = m2 * vc.w; x[2][5] = m2R * r2;

        const int ci = ci0 + c;
#pragma unroll
        for (int i = 0; i < 8; i++) {
            const float* wi = wgt + ((size_t)(cog + i) * Cin + ci) * 9;
            float w00 = wi[0], w01 = wi[1], w02 = wi[2];
            float w10 = wi[3], w11 = wi[4], w12 = wi[5];
            float w20 = wi[6], w21 = wi[7], w22 = wi[8];
#pragma unroll
            for (int j = 0; j < 4; j++) {
                acc[j][i] += x[0][j] * w00 + x[0][j + 1] * w01 + x[0][j + 2] * w02
                           + x[1][j] * w10 + x[1][j + 1] * w11 + x[1][j + 2] * w12
                           + x[2][j] * w20 + x[2][j + 1] * w21 + x[2][j + 2] * w22;
            }
        }
    }

    float* o = acc_out + ((size_t)b * Cout + cog) * HW + h * W + wq;
#pragma unroll
    for (int i = 0; i < 8; i++)
#pragma unroll
        for (int j = 0; j < 4; j++)
            unsafeAtomicAdd(o + i * HW + j, acc[j][i]);
}

// Fused final iwt (12ch -> 3ch, 128->256) + 1x1 conv (3->3, no bias).
__global__ __launch_bounds__(TPB) void final_k(const float* __restrict__ src,
                                               const float* __restrict__ cf,
                                               float* __restrict__ out) {
    int p = blockIdx.x * TPB + threadIdx.x;  // 0..16383 over 128x128
    int b = blockIdx.z;
    int h = p >> 7, w = p & 127;
    const int st = 128 * 128;
    float y00[3], y01[3], y10[3], y11[3];
    const float* r = src + (size_t)b * 12 * st + p;
#pragma unroll
    for (int c = 0; c < 3; c++) {
        float v0 = r[(4 * c) * st];
        float v1 = 2.0f * r[(4 * c + 1) * st] - 1.0f;
        float v2 = 2.0f * r[(4 * c + 2) * st] - 1.0f;
        float v3 = 2.0f * r[(4 * c + 3) * st] - 1.0f;
        y00[c] = v0 + 0.5f * ( v1 + v2 + v3);
        y01[c] = v0 + 0.5f * ( v1 - v2 - v3);
        y10[c] = v0 + 0.5f * (-v1 + v2 - v3);
        y11[c] = v0 + 0.5f * (-v1 - v2 + v3);
    }
#pragma unroll
    for (int o = 0; o < 3; o++) {
        float k0 = cf[o * 3], k1 = cf[o * 3 + 1], k2 = cf[o * 3 + 2];
        float* q = out + (((size_t)b * 3 + o) * 256 + 2 * h) * 256 + 2 * w;
        q[0]   = k0 * y00[0] + k1 * y00[1] + k2 * y00[2];
        q[1]   = k0 * y01[0] + k1 * y01[1] + k2 * y01[2];
        q[256] = k0 * y10[0] + k1 * y10[1] + k2 * y10[2];
        q[257] = k0 * y11[0] + k1 * y11[1] + k2 * y11[2];
    }
}

static inline void conv_launch(const float* s0, int C0, const float* s1,
                               const float* wgt, const float* bias,
                               const float* skip, float* out,
                               int Cin, int Cout, int H, int W,
                               bool has_skip, int CO, hipStream_t st) {
    dim3 grid((H * W + TPB - 1) / TPB, Cout / CO, 4);
    if (CO == 8) {
        if (has_skip)
            conv3x3_k<8, true, true><<<grid, TPB, 0, st>>>(s0, C0, s1, wgt, bias, skip, out, Cin, Cout, H, W);
        else
            conv3x3_k<8, true, false><<<grid, TPB, 0, st>>>(s0, C0, s1, wgt, bias, skip, out, Cin, Cout, H, W);
    } else {
        conv3x3_k<4, true, false><<<grid, TPB, 0, st>>>(s0, C0, s1, wgt, bias, skip, out, Cin, Cout, H, W);
    }
}

extern "C" void kernel_launch(void* const* d_in, const int* in_sizes, int n_in,
                              void* d_out, int out_size, void* d_ws, size_t ws_size,
                              hipStream_t stream) {
    (void)in_sizes; (void)n_in; (void)out_size; (void)ws_size;
    const float* x      = (const float*)d_in[0];
    const float* c1w    = (const float*)d_in[1];
    const float* c1b    = (const float*)d_in[2];
    const float* c2w    = (const float*)d_in[3];
    const float* c2b    = (const float*)d_in[4];
    const float* c3w    = (const float*)d_in[5];
    const float* c3b    = (const float*)d_in[6];
    const float* c4w    = (const float*)d_in[7];
    const float* c4b    = (const float*)d_in[8];
    const float* d4w    = (const float*)d_in[9];
    const float* d4b    = (const float*)d_in[10];
    const float* d3w    = (const float*)d_in[11];
    const float* d3b    = (const float*)d_in[12];
    const float* d2w    = (const float*)d_in[13];
    const float* d2b    = (const float*)d_in[14];
    const float* d1w    = (const float*)d_in[15];
    const float* d1b    = (const float*)d_in[16];
    const float* cfin   = (const float*)d_in[17];
    float* out = (float*)d_out;

    float* ws = (float*)d_ws;
    const size_t M = 1048576;
    float* C1 = ws;
    float* C2 = ws + 1 * M;
    float* C3 = ws + 2 * M;
    float* W4 = ws + 3 * M;
    float* TA = ws + 4 * M;
    float* TB = ws + 5 * M;

    const dim3 g4(128, CONV4_KS, 1);
    const dim3 gE(1024, 1, 4);   // elementwise over 1024*256 per batch

    // 1. w1 = wt(x): (4,3,256,256) -> (4,12,128,128), in TA
    wt_k<<<dim3(3 * 128 * 128 / TPB, 1, 4), TPB, 0, stream>>>(x, TA, 3, 128, 128);
    // 2. c1 = lrelu(conv1(w1)): 12 -> 16 @128^2
    conv_launch(TA, 12, nullptr, c1w, c1b, nullptr, C1, 12, 16, 128, 128, false, 8, stream);
    // 3. w2 = wt(c1): -> (4,64,64,64) in TA
    wt_k<<<dim3(16 * 64 * 64 / TPB, 1, 4), TPB, 0, stream>>>(C1, TA, 16, 64, 64);
    // 4. c2 = lrelu(conv2(w2)): 64 -> 64 @64^2  [tiled]
    bias_init_k<<<gE, TPB, 0, stream>>>(C2, c2b, 64, 4096);
    convt_k<64, 16, 16><<<dim3(8, 4, 16), TPB, 0, stream>>>(TA, 64, nullptr, 64, c2w, C2, 64);
    fin_k<false><<<gE, TPB, 0, stream>>>(C2, nullptr, 262144);
    // 5. w3 = wt(c2): -> (4,256,32,32) in TA
    wt_k<<<dim3(64 * 32 * 32 / TPB, 1, 4), TPB, 0, stream>>>(C2, TA, 64, 32, 32);
    // 6. c3 = lrelu(conv3(w3)): 256 -> 256 @32^2  [tiled]
    bias_init_k<<<gE, TPB, 0, stream>>>(C3, c3b, 256, 1024);
    convt_k<32, 32, 32><<<dim3(32, 8, 4), TPB, 0, stream>>>(TA, 256, nullptr, 256, c3w, C3, 256);
    fin_k<false><<<gE, TPB, 0, stream>>>(C3, nullptr, 262144);
    // 7. w4 = wt(c3): -> (4,1024,16,16) in W4 (kept for skip)
    wt_k<<<dim3(256 * 16 * 16 / TPB, 1, 4), TPB, 0, stream>>>(C3, W4, 256, 16, 16);
    // 8. c4 = lrelu(conv4(w4)) -> TA
    bias_init_k<<<gE, TPB, 0, stream>>>(TA, c4b, 1024, 256);
    conv4_tile_k<<<g4, TPB, 0, stream>>>(W4, c4w, TA);
    fin_k<false><<<gE, TPB, 0, stream>>>(TA, nullptr, 262144);
    // 9. c5 = lrelu(conv4(c4)) -> TB
    bias_init_k<<<gE, TPB, 0, stream>>>(TB, c4b, 1024, 256);
    conv4_tile_k<<<g4, TPB, 0, stream>>>(TA, c4w, TB);
    fin_k<false><<<gE, TPB, 0, stream>>>(TB, nullptr, 262144);
    // 10. ic4 = lrelu(conv4(c5) + w4) -> TA
    bias_init_k<<<gE, TPB, 0, stream>>>(TA, c4b, 1024, 256);
    conv4_tile_k<<<g4, TPB, 0, stream>>>(TB, c4w, TA);
    fin_k<true><<<gE, TPB, 0, stream>>>(TA, W4, 262144);
    // 11. t4 = iwt(ic4): (4,1024,16,16) -> (4,256,32,32) in TB
    iwt_k<<<dim3(256 * 16 * 16 / TPB, 1, 4), TPB, 0, stream>>>(TA, TB, 256, 16, 16);
    // 12. ic3 = lrelu(convd4(c3 || t4)): 512 -> 256 @32^2 -> TA  [tiled]
    bias_init_k<<<gE, TPB, 0, stream>>>(TA, d4b, 256, 1024);
    convt_k<32, 32, 64><<<dim3(32, 8, 4), TPB, 0, stream>>>(C3, 256, TB, 512, d4w, TA, 256);
    fin_k<false><<<gE, TPB, 0, stream>>>(TA, nullptr, 262144);
    // 13. t3 = iwt(ic3): -> (4,64,64,64) in TB
    iwt_k<<<dim3(64 * 32 * 32 / TPB, 1, 4), TPB, 0, stream>>>(TA, TB, 64, 32, 32);
    // 14. ic2 = lrelu(convd3(c2 || t3)): 128 -> 64 @64^2 -> TA  [tiled]
    bias_init_k<<<gE, TPB, 0, stream>>>(TA, d3b, 64, 4096);
    convt_k<64, 16, 32><<<dim3(8, 4, 16), TPB, 0, stream>>>(C2, 64, TB, 128, d3w, TA, 64);
    fin_k<false><<<gE, TPB, 0, stream>>>(TA, nullptr, 262144);
    // 15. t2 = iwt(ic2): -> (4,16,128,128) in TB
    iwt_k<<<dim3(16 * 64 * 64 / TPB, 1, 4), TPB, 0, stream>>>(TA, TB, 16, 64, 64);
    // 16. ic1 = lrelu(convd2(c1 || t2)): 32 -> 16 @128^2 -> TA
    conv_launch(C1, 16, TB, d2w, d2b, nullptr, TA, 32, 16, 128, 128, false, 8, stream);
    // 17. iw1 = lrelu(convd1(ic1)): 16 -> 12 @128^2 -> TB
    conv_launch(TA, 16, TA, d1w, d1b, nullptr, TB, 16, 12, 128, 128, false, 4, stream);
    // 18. out = 1x1(iwt(iw1)) fused
    final_k<<<dim3(128 * 128 / TPB, 1, 4), TPB, 0, stream>>>(TB, cfin, out);
}

// Round 4
// 1143.896 us; speedup vs baseline: 4.6653x; 1.8530x over previous
//
#include <hip/hip_runtime.h>

// ---------------------------------------------------------------------------
// Waveletnet: Haar DWT U-Net.
// R3: conv4 chain (3x 1024->1024 @16x16) moved to fp16 MFMA implicit GEMM:
//   im2col A[m=1024][k=tap*1024+ci] fp16, weights Bh[co][k] fp16 (once),
//   GEMM M=N=1024 K=9216: 128x128 tile, mfma_f32_16x16x32_f16,
//   global_load_lds 16B staging, K-split 8 + unsafeAtomicAdd (bias-preinit).
// conv2/conv3/convd4/convd3 remain fp32 tiled convt_k; small layers generic.
// Workspace (bytes):
//   floats: C1|C2|C3|W4|TA|TB  (6 x 4 MB = 24 MB)
//   then:   Bh 18.9MB | Aim 18.9MB | Cmc 4MB | X0 2MB | X1 2MB   (~70 MB)
// ---------------------------------------------------------------------------

#define TPB 256

typedef _Float16 f16x8 __attribute__((ext_vector_type(8)));
typedef float f32x4 __attribute__((ext_vector_type(4)));

#define GLOAD_LDS16(g, l)                                                     \
    __builtin_amdgcn_global_load_lds(                                         \
        (const __attribute__((address_space(1))) void*)(g),                   \
        (__attribute__((address_space(3))) void*)(l), 16, 0, 0)

__global__ __launch_bounds__(TPB) void wt_k(const float* __restrict__ src,
                                            float* __restrict__ dst,
                                            int C, int H2, int W2) {
    int n = C * H2 * W2;
    int idx = blockIdx.x * TPB + threadIdx.x;
    if (idx >= n) return;
    int b = blockIdx.z;
    int c = idx / (H2 * W2);
    int p = idx - c * (H2 * W2);
    int h = p / W2, w = p - h * W2;
    int W = 2 * W2;
    const float* r = src + (((size_t)b * C + c) * (2 * H2) + 2 * h) * W + 2 * w;
    float a = r[0], bb = r[1], cc = r[W], dd = r[W + 1];
    size_t st = (size_t)H2 * W2;
    float* o = dst + (((size_t)b * 4 * C + 4 * c) * st) + p;
    o[0]      = 0.25f * (a + bb + cc + dd);
    o[st]     = (0.5f * (a + bb - cc - dd) + 1.0f) * 0.5f;
    o[2 * st] = (0.5f * (a - bb + cc - dd) + 1.0f) * 0.5f;
    o[3 * st] = (0.5f * (a - bb - cc + dd) + 1.0f) * 0.5f;
}

__global__ __launch_bounds__(TPB) void iwt_k(const float* __restrict__ src,
                                             float* __restrict__ dst,
                                             int C, int H, int W) {
    int n = C * H * W;
    int idx = blockIdx.x * TPB + threadIdx.x;
    if (idx >= n) return;
    int b = blockIdx.z;
    int c = idx / (H * W);
    int p = idx - c * (H * W);
    int h = p / W, w = p - h * W;
    size_t st = (size_t)H * W;
    const float* r = src + ((size_t)b * 4 * C + 4 * c) * st + p;
    float v0 = r[0];
    float v1 = 2.0f * r[st] - 1.0f;
    float v2 = 2.0f * r[2 * st] - 1.0f;
    float v3 = 2.0f * r[3 * st] - 1.0f;
    float* o = dst + (((size_t)b * C + c) * (2 * H) + 2 * h) * (2 * W) + 2 * w;
    o[0]         = v0 + 0.5f * ( v1 + v2 + v3);
    o[1]         = v0 + 0.5f * ( v1 - v2 - v3);
    o[2 * W]     = v0 + 0.5f * (-v1 + v2 - v3);
    o[2 * W + 1] = v0 + 0.5f * (-v1 - v2 + v3);
}

// Generic direct 3x3 conv — conv1, convd2, convd1 only.
template <int CO, bool LRELU, bool HAS_SKIP>
__global__ __launch_bounds__(TPB) void conv3x3_k(
    const float* __restrict__ s0, int C0,
    const float* __restrict__ s1,
    const float* __restrict__ wgt, const float* __restrict__ bias,
    const float* __restrict__ skip,
    float* __restrict__ out,
    int Cin, int Cout, int H, int W) {
    const int hw = H * W;
    int p = blockIdx.x * TPB + threadIdx.x;
    if (p >= hw) return;
    const int b = blockIdx.z;
    const int cog = blockIdx.y * CO;
    const int h = p / W, w = p - (p / W) * W;
    const bool hm = h > 0, hp = h < H - 1, wm = w > 0, wpp = w < W - 1;

    float acc[CO];
#pragma unroll
    for (int i = 0; i < CO; i++) acc[i] = bias[cog + i];

    const int C1n = Cin - C0;
    for (int ci = 0; ci < Cin; ci++) {
        const float* sp = (ci < C0)
            ? s0 + ((size_t)b * C0 + ci) * hw
            : s1 + ((size_t)b * C1n + (ci - C0)) * hw;
        const float* r = sp + p;
        float x00 = (hm && wm)  ? r[-W - 1] : 0.0f;
        float x01 = hm          ? r[-W]     : 0.0f;
        float x02 = (hm && wpp) ? r[-W + 1] : 0.0f;
        float x10 = wm          ? r[-1]     : 0.0f;
        float x11 =               r[0];
        float x12 = wpp         ? r[1]      : 0.0f;
        float x20 = (hp && wm)  ? r[W - 1]  : 0.0f;
        float x21 = hp          ? r[W]      : 0.0f;
        float x22 = (hp && wpp) ? r[W + 1]  : 0.0f;
        const float* wk = wgt + ((size_t)cog * Cin + ci) * 9;
#pragma unroll
        for (int i = 0; i < CO; i++) {
            const float* wi = wk + (size_t)i * Cin * 9;
            acc[i] += x00 * wi[0] + x01 * wi[1] + x02 * wi[2]
                    + x10 * wi[3] + x11 * wi[4] + x12 * wi[5]
                    + x20 * wi[6] + x21 * wi[7] + x22 * wi[8];
        }
    }
#pragma unroll
    for (int i = 0; i < CO; i++) {
        float v = acc[i];
        if (HAS_SKIP) v += skip[((size_t)b * Cout + cog + i) * hw + p];
        if (LRELU) v = (v >= 0.0f) ? v : 0.2f * v;
        out[((size_t)b * Cout + cog + i) * hw + p] = v;
    }
}

// ---- helpers for K-split conv path (fp32 tiled convs) ----------------------

__global__ __launch_bounds__(TPB) void bias_init_k(float* __restrict__ out,
                                                   const float* __restrict__ bias,
                                                   int C, int HW) {
    int idx = blockIdx.x * TPB + threadIdx.x;
    int b = blockIdx.z;
    int c = idx / HW;
    out[((size_t)b * C + c) * HW + (idx - c * HW)] = bias[c];
}

template <bool HAS_SKIP>
__global__ __launch_bounds__(TPB) void fin_k(float* __restrict__ buf,
                                             const float* __restrict__ skip,
                                             int n) {
    size_t i = (size_t)blockIdx.x * TPB + threadIdx.x + (size_t)blockIdx.z * n;
    float v = buf[i];
    if (HAS_SKIP) v += skip[i];
    buf[i] = (v >= 0.0f) ? v : 0.2f * v;
}

// ---- generalized fp32 tiled K-split conv (conv2, conv3, convd4, convd3) ----
template <int W, int ROWS, int CI_CHUNK>
__global__ __launch_bounds__(TPB) void convt_k(
    const float* __restrict__ s0, int C0,
    const float* __restrict__ s1, int Cin,
    const float* __restrict__ wgt,
    float* __restrict__ acc_out, int Cout) {
    const int HW = W * W;
    const int QPR = W / 4;
    const int RT = W / ROWS;
    const int t = threadIdx.x;
    const int z = blockIdx.z;
    const int b = z / RT;
    const int rt = z - b * RT;
    const int h = rt * ROWS + t / QPR;
    const int wq = (t - (t / QPR) * QPR) * 4;
    const int cog = blockIdx.x << 3;
    const int ci0 = blockIdx.y * CI_CHUNK;

    const float* src = (ci0 < C0)
        ? s0 + ((size_t)b * C0 + ci0) * HW
        : s1 + ((size_t)b * (Cin - C0) + (ci0 - C0)) * HW;

    const int off0 = (h > 0) ? -W : 0;
    const int off2 = (h < W - 1) ? W : 0;
    const int offL = (wq > 0) ? -1 : 0;
    const int offR = (wq < W - 4) ? 4 : 3;
    const float m0 = (h > 0) ? 1.0f : 0.0f;
    const float m2 = (h < W - 1) ? 1.0f : 0.0f;
    const float mL = (wq > 0) ? 1.0f : 0.0f;
    const float mR = (wq < W - 4) ? 1.0f : 0.0f;
    const float m0L = m0 * mL, m0R = m0 * mR, m2L = m2 * mL, m2R = m2 * mR;

    float acc[4][8];
#pragma unroll
    for (int j = 0; j < 4; j++)
#pragma unroll
        for (int i = 0; i < 8; i++) acc[j][i] = 0.0f;

    const float* p0 = src + h * W + wq;

#pragma unroll 2
    for (int c = 0; c < CI_CHUNK; ++c) {
        const float* p = p0 + (size_t)c * HW;
        float4 va = *(const float4*)(p + off0);
        float4 vb = *(const float4*)(p);
        float4 vc = *(const float4*)(p + off2);
        float l0 = p[off0 + offL], r0 = p[off0 + offR];
        float l1 = p[offL],        r1 = p[offR];
        float l2 = p[off2 + offL], r2 = p[off2 + offR];
        float x[3][6];
        x[0][0] = m0L * l0; x[0][1] = m0 * va.x; x[0][2] = m0 * va.y;
        x[0][3] = m0 * va.z; x[0][4] = m0 * va.w; x[0][5] = m0R * r0;
        x[1][0] = mL * l1;  x[1][1] = vb.x; x[1][2] = vb.y;
        x[1][3] = vb.z;     x[1][4] = vb.w; x[1][5] = mR * r1;
        x[2][0] = m2L * l2; x[2][1] = m2 * vc.x; x[2][2] = m2 * vc.y;
        x[2][3] = m2 * vc.z; x[2][4] = m2 * vc.w; x[2][5] = m2R * r2;

        const int ci = ci0 + c;
#pragma unroll
        for (int i = 0; i < 8; i++) {
            const float* wi = wgt + ((size_t)(cog + i) * Cin + ci) * 9;
            float w00 = wi[0], w01 = wi[1], w02 = wi[2];
            float w10 = wi[3], w11 = wi[4], w12 = wi[5];
            float w20 = wi[6], w21 = wi[7], w22 = wi[8];
#pragma unroll
            for (int j = 0; j < 4; j++) {
                acc[j][i] += x[0][j] * w00 + x[0][j + 1] * w01 + x[0][j + 2] * w02
                           + x[1][j] * w10 + x[1][j + 1] * w11 + x[1][j + 2] * w12
                           + x[2][j] * w20 + x[2][j + 1] * w21 + x[2][j + 2] * w22;
            }
        }
    }

    float* o = acc_out + ((size_t)b * Cout + cog) * HW + h * W + wq;
#pragma unroll
    for (int i = 0; i < 8; i++)
#pragma unroll
        for (int j = 0; j < 4; j++)
            unsafeAtomicAdd(o + i * HW + j, acc[j][i]);
}

// ---- conv4 MFMA path -------------------------------------------------------

// X[m][ci] fp16  <-  W4 spatial [b,ci,16,16] fp32   (m = b*256 + p)
__global__ __launch_bounds__(TPB) void w4_to_x_k(const float* __restrict__ W4,
                                                 _Float16* __restrict__ X) {
    int idx = blockIdx.x * TPB + threadIdx.x;   // over 1M
    int m = idx >> 10, ci = idx & 1023;
    int b = m >> 8, p = m & 255;
    X[idx] = (_Float16)W4[(((size_t)b << 10) + ci) * 256 + p];
}

// Bh[co][tap*1024+ci] fp16  <-  w[co][ci][tap] fp32   (once per launch)
__global__ __launch_bounds__(TPB) void wtrans_k(const float* __restrict__ w,
                                                _Float16* __restrict__ Bh) {
    int idx = blockIdx.x * TPB + threadIdx.x;   // over 9216*1024
    int co = idx / 9216;
    int r = idx - co * 9216;
    int tap = r >> 10, ci = r & 1023;
    Bh[idx] = (_Float16)w[((size_t)co * 1024 + ci) * 9 + tap];
}

// A[m][tap*1024+ci] = X[m_nb(tap)][ci] or 0.  grid (1024, 9), block 128.
__global__ __launch_bounds__(128) void im2col_k(const _Float16* __restrict__ X,
                                                _Float16* __restrict__ A) {
    const int m = blockIdx.x, tap = blockIdx.y, t = threadIdx.x;
    const int h = (m >> 4) & 15, w = m & 15, b = m >> 8;
    const int hh = h + tap / 3 - 1, ww = w + tap % 3 - 1;
    f16x8* dst = (f16x8*)(A + (size_t)m * 9216 + tap * 1024) + t;
    if ((unsigned)hh < 16u && (unsigned)ww < 16u) {
        const f16x8* src = (const f16x8*)(X + (size_t)((b << 8) + (hh << 4) + ww) * 1024) + t;
        *dst = *src;
    } else {
        f16x8 z = {0, 0, 0, 0, 0, 0, 0, 0};
        *dst = z;
    }
}

// C[m][co] = bias[co]
__global__ __launch_bounds__(TPB) void bias_init_mc_k(float* __restrict__ C,
                                                      const float* __restrict__ bias) {
    int idx = blockIdx.x * TPB + threadIdx.x;   // over 1M
    C[idx] = bias[idx & 1023];
}

// GEMM: C[m][n] += sum_k A[m][k] * B[n][k]   (both K-contiguous fp16)
// M=N=1024, K=9216.  grid (8, 8, KS=8), block 256 (4 waves, 2x2 of 64x64).
__global__ __launch_bounds__(TPB) void gemm_k(const _Float16* __restrict__ A,
                                              const _Float16* __restrict__ B,
                                              float* __restrict__ C) {
    const int K = 9216;
    const int ITERS = 36;           // 9216 / 8 splits / 32
    const int m0 = blockIdx.x * 128, n0 = blockIdx.y * 128;
    const int k0 = blockIdx.z * (K / 8);

    __shared__ _Float16 As[128 * 32];
    __shared__ _Float16 Bs[128 * 32];

    const int tid = threadIdx.x;
    const int wave = tid >> 6, lane = tid & 63;
    const int wm = (wave >> 1) * 64, wn = (wave & 1) * 64;

    f32x4 acc[4][4];
#pragma unroll
    for (int i = 0; i < 4; i++)
#pragma unroll
        for (int j = 0; j < 4; j++) acc[i][j] = {0.f, 0.f, 0.f, 0.f};

    // staging: 8 KB per tile, 256 thr x 16 B -> 2 instrs per tile
    const int f0 = tid * 16;            // bytes, instr 0
    const int f1 = f0 + 4096;           // instr 1
    const int rowA0 = f0 >> 6, rbA0 = f0 & 63;
    const int rowA1 = f1 >> 6, rbA1 = f1 & 63;
    const char* gA0 = (const char*)A + ((size_t)(m0 + rowA0) * K + k0) * 2 + rbA0;
    const char* gA1 = (const char*)A + ((size_t)(m0 + rowA1) * K + k0) * 2 + rbA1;
    const char* gB0 = (const char*)B + ((size_t)(n0 + rowA0) * K + k0) * 2 + rbA0;
    const char* gB1 = (const char*)B + ((size_t)(n0 + rowA1) * K + k0) * 2 + rbA1;
    char* lA0 = (char*)As + f0;
    char* lA1 = (char*)As + f1;
    char* lB0 = (char*)Bs + f0;
    char* lB1 = (char*)Bs + f1;

    const int frow = lane & 15;          // fragment row within 16
    const int fk = (lane >> 4) * 8;      // fragment k offset

    for (int it = 0; it < ITERS; ++it) {
        GLOAD_LDS16(gA0, lA0);
        GLOAD_LDS16(gA1, lA1);
        GLOAD_LDS16(gB0, lB0);
        GLOAD_LDS16(gB1, lB1);
        gA0 += 64; gA1 += 64; gB0 += 64; gB1 += 64;
        __syncthreads();

        f16x8 af[4], bf[4];
#pragma unroll
        for (int mt = 0; mt < 4; mt++)
            af[mt] = *(const f16x8*)&As[(wm + mt * 16 + frow) * 32 + fk];
#pragma unroll
        for (int nt = 0; nt < 4; nt++)
            bf[nt] = *(const f16x8*)&Bs[(wn + nt * 16 + frow) * 32 + fk];
#pragma unroll
        for (int mt = 0; mt < 4; mt++)
#pragma unroll
            for (int nt = 0; nt < 4; nt++)
                acc[mt][nt] = __builtin_amdgcn_mfma_f32_16x16x32_f16(
                    af[mt], bf[nt], acc[mt][nt], 0, 0, 0);
        __syncthreads();
    }

    // epilogue: C/D layout col = lane&15, row = (lane>>4)*4 + reg
    const int cm = m0 + wm + (lane >> 4) * 4;
    const int cn = n0 + wn + (lane & 15);
#pragma unroll
    for (int mt = 0; mt < 4; mt++)
#pragma unroll
        for (int nt = 0; nt < 4; nt++)
#pragma unroll
            for (int r = 0; r < 4; r++)
                unsafeAtomicAdd(&C[(size_t)(cm + mt * 16 + r) * 1024 + cn + nt * 16],
                                acc[mt][nt][r]);
}

// X[m][c] fp16 = lrelu(C[m][c])
__global__ __launch_bounds__(TPB) void fin_x_k(const float* __restrict__ C,
                                               _Float16* __restrict__ X) {
    int idx = blockIdx.x * TPB + threadIdx.x;   // over 1M
    float v = C[idx];
    X[idx] = (_Float16)((v >= 0.0f) ? v : 0.2f * v);
}

// out spatial [b,c,p] fp32 = lrelu(C[m][c] + W4[b,c,p])
__global__ __launch_bounds__(TPB) void fin_sp_k(const float* __restrict__ C,
                                                const float* __restrict__ W4,
                                                float* __restrict__ out) {
    int idx = blockIdx.x * TPB + threadIdx.x;   // over 1M, (b,c,p)
    int b = idx >> 18;
    int r = idx & 262143;
    int c = r >> 8, p = r & 255;
    int m = (b << 8) + p;
    float v = C[(size_t)m * 1024 + c] + W4[idx];
    out[idx] = (v >= 0.0f) ? v : 0.2f * v;
}

// Fused final iwt (12ch -> 3ch, 128->256) + 1x1 conv (3->3, no bias).
__global__ __launch_bounds__(TPB) void final_k(const float* __restrict__ src,
                                               const float* __restrict__ cf,
                                               float* __restrict__ out) {
    int p = blockIdx.x * TPB + threadIdx.x;
    int b = blockIdx.z;
    int h = p >> 7, w = p & 127;
    const int st = 128 * 128;
    float y00[3], y01[3], y10[3], y11[3];
    const float* r = src + (size_t)b * 12 * st + p;
#pragma unroll
    for (int c = 0; c < 3; c++) {
        float v0 = r[(4 * c) * st];
        float v1 = 2.0f * r[(4 * c + 1) * st] - 1.0f;
        float v2 = 2.0f * r[(4 * c + 2) * st] - 1.0f;
        float v3 = 2.0f * r[(4 * c + 3) * st] - 1.0f;
        y00[c] = v0 + 0.5f * ( v1 + v2 + v3);
        y01[c] = v0 + 0.5f * ( v1 - v2 - v3);
        y10[c] = v0 + 0.5f * (-v1 + v2 - v3);
        y11[c] = v0 + 0.5f * (-v1 - v2 + v3);
    }
#pragma unroll
    for (int o = 0; o < 3; o++) {
        float k0 = cf[o * 3], k1 = cf[o * 3 + 1], k2 = cf[o * 3 + 2];
        float* q = out + (((size_t)b * 3 + o) * 256 + 2 * h) * 256 + 2 * w;
        q[0]   = k0 * y00[0] + k1 * y00[1] + k2 * y00[2];
        q[1]   = k0 * y01[0] + k1 * y01[1] + k2 * y01[2];
        q[256] = k0 * y10[0] + k1 * y10[1] + k2 * y10[2];
        q[257] = k0 * y11[0] + k1 * y11[1] + k2 * y11[2];
    }
}

static inline void conv_launch(const float* s0, int C0, const float* s1,
                               const float* wgt, const float* bias,
                               const float* skip, float* out,
                               int Cin, int Cout, int H, int W,
                               bool has_skip, int CO, hipStream_t st) {
    dim3 grid((H * W + TPB - 1) / TPB, Cout / CO, 4);
    if (CO == 8) {
        if (has_skip)
            conv3x3_k<8, true, true><<<grid, TPB, 0, st>>>(s0, C0, s1, wgt, bias, skip, out, Cin, Cout, H, W);
        else
            conv3x3_k<8, true, false><<<grid, TPB, 0, st>>>(s0, C0, s1, wgt, bias, skip, out, Cin, Cout, H, W);
    } else {
        conv3x3_k<4, true, false><<<grid, TPB, 0, st>>>(s0, C0, s1, wgt, bias, skip, out, Cin, Cout, H, W);
    }
}

extern "C" void kernel_launch(void* const* d_in, const int* in_sizes, int n_in,
                              void* d_out, int out_size, void* d_ws, size_t ws_size,
                              hipStream_t stream) {
    (void)in_sizes; (void)n_in; (void)out_size; (void)ws_size;
    const float* x      = (const float*)d_in[0];
    const float* c1w    = (const float*)d_in[1];
    const float* c1b    = (const float*)d_in[2];
    const float* c2w    = (const float*)d_in[3];
    const float* c2b    = (const float*)d_in[4];
    const float* c3w    = (const float*)d_in[5];
    const float* c3b    = (const float*)d_in[6];
    const float* c4w    = (const float*)d_in[7];
    const float* c4b    = (const float*)d_in[8];
    const float* d4w    = (const float*)d_in[9];
    const float* d4b    = (const float*)d_in[10];
    const float* d3w    = (const float*)d_in[11];
    const float* d3b    = (const float*)d_in[12];
    const float* d2w    = (const float*)d_in[13];
    const float* d2b    = (const float*)d_in[14];
    const float* d1w    = (const float*)d_in[15];
    const float* d1b    = (const float*)d_in[16];
    const float* cfin   = (const float*)d_in[17];
    float* out = (float*)d_out;

    float* ws = (float*)d_ws;
    const size_t M = 1048576;
    float* C1 = ws;
    float* C2 = ws + 1 * M;
    float* C3 = ws + 2 * M;
    float* W4 = ws + 3 * M;
    float* TA = ws + 4 * M;
    float* TB = ws + 5 * M;
    char* xb = (char*)(ws + 6 * M);
    _Float16* Bh  = (_Float16*)xb;                          // 18,874,368 B
    _Float16* Aim = (_Float16*)(xb + 18874368);             // 18,874,368 B
    float*    Cmc = (float*)(xb + 2 * 18874368);            // 4 MB
    _Float16* X0  = (_Float16*)(xb + 2 * 18874368 + 4194304);
    _Float16* X1  = (_Float16*)(xb + 2 * 18874368 + 4194304 + 2097152);

    const dim3 gE(1024, 1, 4);        // elementwise over 1024*256 per batch
    const dim3 gI2C(1024, 9, 1);      // im2col
    const dim3 gG(8, 8, 8);           // gemm

    // weight transform for conv4 (reused by all 3 layers)
    wtrans_k<<<36864, TPB, 0, stream>>>(c4w, Bh);

    // 1. w1 = wt(x)
    wt_k<<<dim3(3 * 128 * 128 / TPB, 1, 4), TPB, 0, stream>>>(x, TA, 3, 128, 128);
    // 2. c1 = lrelu(conv1(w1)): 12 -> 16 @128^2
    conv_launch(TA, 12, nullptr, c1w, c1b, nullptr, C1, 12, 16, 128, 128, false, 8, stream);
    // 3. w2 = wt(c1)
    wt_k<<<dim3(16 * 64 * 64 / TPB, 1, 4), TPB, 0, stream>>>(C1, TA, 16, 64, 64);
    // 4. c2 = lrelu(conv2(w2)): 64 -> 64 @64^2  [tiled fp32]
    bias_init_k<<<gE, TPB, 0, stream>>>(C2, c2b, 64, 4096);
    convt_k<64, 16, 16><<<dim3(8, 4, 16), TPB, 0, stream>>>(TA, 64, nullptr, 64, c2w, C2, 64);
    fin_k<false><<<gE, TPB, 0, stream>>>(C2, nullptr, 262144);
    // 5. w3 = wt(c2)
    wt_k<<<dim3(64 * 32 * 32 / TPB, 1, 4), TPB, 0, stream>>>(C2, TA, 64, 32, 32);
    // 6. c3 = lrelu(conv3(w3)): 256 -> 256 @32^2  [tiled fp32]
    bias_init_k<<<gE, TPB, 0, stream>>>(C3, c3b, 256, 1024);
    convt_k<32, 32, 32><<<dim3(32, 8, 4), TPB, 0, stream>>>(TA, 256, nullptr, 256, c3w, C3, 256);
    fin_k<false><<<gE, TPB, 0, stream>>>(C3, nullptr, 262144);
    // 7. w4 = wt(c3) -> W4 spatial (kept for skip)
    wt_k<<<dim3(256 * 16 * 16 / TPB, 1, 4), TPB, 0, stream>>>(C3, W4, 256, 16, 16);

    // ---- conv4 chain on MFMA ----
    w4_to_x_k<<<4096, TPB, 0, stream>>>(W4, X0);
    // 8. c4 = lrelu(conv4(w4)) -> X1
    im2col_k<<<gI2C, 128, 0, stream>>>(X0, Aim);
    bias_init_mc_k<<<4096, TPB, 0, stream>>>(Cmc, c4b);
    gemm_k<<<gG, TPB, 0, stream>>>(Aim, Bh, Cmc);
    fin_x_k<<<4096, TPB, 0, stream>>>(Cmc, X1);
    // 9. c5 = lrelu(conv4(c4)) -> X0
    im2col_k<<<gI2C, 128, 0, stream>>>(X1, Aim);
    bias_init_mc_k<<<4096, TPB, 0, stream>>>(Cmc, c4b);
    gemm_k<<<gG, TPB, 0, stream>>>(Aim, Bh, Cmc);
    fin_x_k<<<4096, TPB, 0, stream>>>(Cmc, X0);
    // 10. ic4 = lrelu(conv4(c5) + w4) -> TA (spatial fp32)
    im2col_k<<<gI2C, 128, 0, stream>>>(X0, Aim);
    bias_init_mc_k<<<4096, TPB, 0, stream>>>(Cmc, c4b);
    gemm_k<<<gG, TPB, 0, stream>>>(Aim, Bh, Cmc);
    fin_sp_k<<<4096, TPB, 0, stream>>>(Cmc, W4, TA);

    // 11. t4 = iwt(ic4): -> (4,256,32,32) in TB
    iwt_k<<<dim3(256 * 16 * 16 / TPB, 1, 4), TPB, 0, stream>>>(TA, TB, 256, 16, 16);
    // 12. ic3 = lrelu(convd4(c3 || t4)): 512 -> 256 @32^2 -> TA  [tiled fp32]
    bias_init_k<<<gE, TPB, 0, stream>>>(TA, d4b, 256, 1024);
    convt_k<32, 32, 64><<<dim3(32, 8, 4), TPB, 0, stream>>>(C3, 256, TB, 512, d4w, TA, 256);
    fin_k<false><<<gE, TPB, 0, stream>>>(TA, nullptr, 262144);
    // 13. t3 = iwt(ic3): -> (4,64,64,64) in TB
    iwt_k<<<dim3(64 * 32 * 32 / TPB, 1, 4), TPB, 0, stream>>>(TA, TB, 64, 32, 32);
    // 14. ic2 = lrelu(convd3(c2 || t3)): 128 -> 64 @64^2 -> TA  [tiled fp32]
    bias_init_k<<<gE, TPB, 0, stream>>>(TA, d3b, 64, 4096);
    convt_k<64, 16, 32><<<dim3(8, 4, 16), TPB, 0, stream>>>(C2, 64, TB, 128, d3w, TA, 64);
    fin_k<false><<<gE, TPB, 0, stream>>>(TA, nullptr, 262144);
    // 15. t2 = iwt(ic2): -> (4,16,128,128) in TB
    iwt_k<<<dim3(16 * 64 * 64 / TPB, 1, 4), TPB, 0, stream>>>(TA, TB, 16, 64, 64);
    // 16. ic1 = lrelu(convd2(c1 || t2)): 32 -> 16 @128^2 -> TA
    conv_launch(C1, 16, TB, d2w, d2b, nullptr, TA, 32, 16, 128, 128, false, 8, stream);
    // 17. iw1 = lrelu(convd1(ic1)): 16 -> 12 @128^2 -> TB
    conv_launch(TA, 16, TA, d1w, d1b, nullptr, TB, 16, 12, 128, 128, false, 4, stream);
    // 18. out = 1x1(iwt(iw1)) fused
    final_k<<<dim3(128 * 128 / TPB, 1, 4), TPB, 0, stream>>>(TB, cfin, out);
}

// Round 6
// 638.682 us; speedup vs baseline: 8.3557x; 1.7910x over previous
//
#include <hip/hip_runtime.h>

// ---------------------------------------------------------------------------
// Waveletnet: Haar DWT U-Net.
// R6 = R5 with the convd4 weight-transform launch fixed (n was 2x too big ->
// OOB read of d4w -> HSA abort). All large convs (conv2..conv4 chain, convd4,
// convd3) on fp16 MFMA implicit GEMM with FUSED im2col: cgemm_k<LC,NT> stages
// A-tiles directly from channels-last fp16 X via ds_write (tap/border math
// in-kernel); B (weights, [co][tap*C+ci] fp16) staged via global_load_lds 16B.
// K-split + unsafeAtomicAdd into bias-preinit C, fin applies lrelu and writes
// spatial fp32 and/or channels-last fp16 (concat via channel offset).
// Small layers (conv1, convd2, convd1) stay on the generic fp32 kernel.
// Workspace (<= 67 MB): see offsets in kernel_launch.
// ---------------------------------------------------------------------------

#define TPB 256

typedef _Float16 f16x8 __attribute__((ext_vector_type(8)));
typedef float f32x4 __attribute__((ext_vector_type(4)));

#define GLOAD_LDS16(g, l)                                                     \
    __builtin_amdgcn_global_load_lds(                                         \
        (const __attribute__((address_space(1))) void*)(g),                   \
        (__attribute__((address_space(3))) void*)(l), 16, 0, 0)

// ---- spatial wt (fp32 -> fp32), used for step1 and W4 ----------------------
__global__ __launch_bounds__(TPB) void wt_k(const float* __restrict__ src,
                                            float* __restrict__ dst,
                                            int C, int H2, int W2) {
    int n = C * H2 * W2;
    int idx = blockIdx.x * TPB + threadIdx.x;
    if (idx >= n) return;
    int b = blockIdx.z;
    int c = idx / (H2 * W2);
    int p = idx - c * (H2 * W2);
    int h = p / W2, w = p - h * W2;
    int W = 2 * W2;
    const float* r = src + (((size_t)b * C + c) * (2 * H2) + 2 * h) * W + 2 * w;
    float a = r[0], bb = r[1], cc = r[W], dd = r[W + 1];
    size_t st = (size_t)H2 * W2;
    float* o = dst + (((size_t)b * 4 * C + 4 * c) * st) + p;
    o[0]      = 0.25f * (a + bb + cc + dd);
    o[st]     = (0.5f * (a + bb - cc - dd) + 1.0f) * 0.5f;
    o[2 * st] = (0.5f * (a - bb + cc - dd) + 1.0f) * 0.5f;
    o[3 * st] = (0.5f * (a - bb - cc + dd) + 1.0f) * 0.5f;
}

// ---- wt: spatial fp32 in -> channels-last fp16 out -------------------------
// LC = log2(C_in). Out: X[(b*H2W2 + p)*4C + 4c+k]
template <int LC>
__global__ __launch_bounds__(TPB) void wt_cl_k(const float* __restrict__ src,
                                               _Float16* __restrict__ X,
                                               int H2, int W2) {
    const int C = 1 << LC;
    int idx = blockIdx.x * TPB + threadIdx.x;   // over H2*W2*C
    int b = blockIdx.z;
    int c = idx & (C - 1);
    int p = idx >> LC;
    if (p >= H2 * W2) return;
    int h = p / W2, w = p - h * W2;
    int W = 2 * W2;
    const float* r = src + (((size_t)b * C + c) * (2 * H2) + 2 * h) * W + 2 * w;
    float a = r[0], bb = r[1], cc = r[W], dd = r[W + 1];
    _Float16* o = X + ((size_t)(b * H2 * W2 + p)) * (4 * C) + 4 * c;
    o[0] = (_Float16)(0.25f * (a + bb + cc + dd));
    o[1] = (_Float16)((0.5f * (a + bb - cc - dd) + 1.0f) * 0.5f);
    o[2] = (_Float16)((0.5f * (a - bb + cc - dd) + 1.0f) * 0.5f);
    o[3] = (_Float16)((0.5f * (a - bb - cc + dd) + 1.0f) * 0.5f);
}

// ---- spatial iwt (fp32 -> fp32), used before convd2 ------------------------
__global__ __launch_bounds__(TPB) void iwt_k(const float* __restrict__ src,
                                             float* __restrict__ dst,
                                             int C, int H, int W) {
    int n = C * H * W;
    int idx = blockIdx.x * TPB + threadIdx.x;
    if (idx >= n) return;
    int b = blockIdx.z;
    int c = idx / (H * W);
    int p = idx - c * (H * W);
    int h = p / W, w = p - h * W;
    size_t st = (size_t)H * W;
    const float* r = src + ((size_t)b * 4 * C + 4 * c) * st + p;
    float v0 = r[0];
    float v1 = 2.0f * r[st] - 1.0f;
    float v2 = 2.0f * r[2 * st] - 1.0f;
    float v3 = 2.0f * r[3 * st] - 1.0f;
    float* o = dst + (((size_t)b * C + c) * (2 * H) + 2 * h) * (2 * W) + 2 * w;
    o[0]         = v0 + 0.5f * ( v1 + v2 + v3);
    o[1]         = v0 + 0.5f * ( v1 - v2 - v3);
    o[2 * W]     = v0 + 0.5f * (-v1 + v2 - v3);
    o[2 * W + 1] = v0 + 0.5f * (-v1 - v2 + v3);
}

// ---- iwt: spatial fp32 in -> channels-last fp16 out (into concat slice) ----
// LC = log2(C_out). Input (B, 4C, H, W); output res 2H x 2W, X[m*Ctot+Coff+c].
template <int LC>
__global__ __launch_bounds__(TPB) void iwt_cl_k(const float* __restrict__ src,
                                                _Float16* __restrict__ X,
                                                int H, int W, int Coff, int Ctot) {
    const int C = 1 << LC;
    int idx = blockIdx.x * TPB + threadIdx.x;   // over H*W*C
    int b = blockIdx.z;
    int c = idx & (C - 1);
    int p = idx >> LC;
    if (p >= H * W) return;
    int h = p / W, w = p - h * W;
    size_t st = (size_t)H * W;
    const float* r = src + ((size_t)b * 4 * C + 4 * c) * st + p;
    float v0 = r[0];
    float v1 = 2.0f * r[st] - 1.0f;
    float v2 = 2.0f * r[2 * st] - 1.0f;
    float v3 = 2.0f * r[3 * st] - 1.0f;
    size_t mb = (size_t)b * 4 * H * W + (size_t)(2 * h) * (2 * W) + 2 * w;
    _Float16* o = X + mb * Ctot + Coff + c;
    o[0]                          = (_Float16)(v0 + 0.5f * ( v1 + v2 + v3));
    o[(size_t)Ctot]               = (_Float16)(v0 + 0.5f * ( v1 - v2 - v3));
    o[(size_t)(2 * W) * Ctot]     = (_Float16)(v0 + 0.5f * (-v1 + v2 - v3));
    o[(size_t)(2 * W + 1) * Ctot] = (_Float16)(v0 + 0.5f * (-v1 - v2 + v3));
}

// ---- generic direct 3x3 conv (conv1, convd2, convd1) -----------------------
template <int CO, bool LRELU, bool HAS_SKIP>
__global__ __launch_bounds__(TPB) void conv3x3_k(
    const float* __restrict__ s0, int C0,
    const float* __restrict__ s1,
    const float* __restrict__ wgt, const float* __restrict__ bias,
    const float* __restrict__ skip,
    float* __restrict__ out,
    int Cin, int Cout, int H, int W) {
    const int hw = H * W;
    int p = blockIdx.x * TPB + threadIdx.x;
    if (p >= hw) return;
    const int b = blockIdx.z;
    const int cog = blockIdx.y * CO;
    const int h = p / W, w = p - (p / W) * W;
    const bool hm = h > 0, hp = h < H - 1, wm = w > 0, wpp = w < W - 1;

    float acc[CO];
#pragma unroll
    for (int i = 0; i < CO; i++) acc[i] = bias[cog + i];

    const int C1n = Cin - C0;
    for (int ci = 0; ci < Cin; ci++) {
        const float* sp = (ci < C0)
            ? s0 + ((size_t)b * C0 + ci) * hw
            : s1 + ((size_t)b * C1n + (ci - C0)) * hw;
        const float* r = sp + p;
        float x00 = (hm && wm)  ? r[-W - 1] : 0.0f;
        float x01 = hm          ? r[-W]     : 0.0f;
        float x02 = (hm && wpp) ? r[-W + 1] : 0.0f;
        float x10 = wm          ? r[-1]     : 0.0f;
        float x11 =               r[0];
        float x12 = wpp         ? r[1]      : 0.0f;
        float x20 = (hp && wm)  ? r[W - 1]  : 0.0f;
        float x21 = hp          ? r[W]      : 0.0f;
        float x22 = (hp && wpp) ? r[W + 1]  : 0.0f;
        const float* wk = wgt + ((size_t)cog * Cin + ci) * 9;
#pragma unroll
        for (int i = 0; i < CO; i++) {
            const float* wi = wk + (size_t)i * Cin * 9;
            acc[i] += x00 * wi[0] + x01 * wi[1] + x02 * wi[2]
                    + x10 * wi[3] + x11 * wi[4] + x12 * wi[5]
                    + x20 * wi[6] + x21 * wi[7] + x22 * wi[8];
        }
    }
#pragma unroll
    for (int i = 0; i < CO; i++) {
        float v = acc[i];
        if (HAS_SKIP) v += skip[((size_t)b * Cout + cog + i) * hw + p];
        if (LRELU) v = (v >= 0.0f) ? v : 0.2f * v;
        out[((size_t)b * Cout + cog + i) * hw + p] = v;
    }
}

// ---- MFMA GEMM path helpers ------------------------------------------------

// Bh[co][tap*Cin+ci] fp16  <-  w[co][ci][tap] fp32;  n = Cout*9*Cin
__global__ __launch_bounds__(TPB) void wtrans_g_k(const float* __restrict__ w,
                                                  _Float16* __restrict__ Bh,
                                                  int Cin, int n) {
    int idx = blockIdx.x * TPB + threadIdx.x;
    if (idx >= n) return;
    int K = 9 * Cin;
    int co = idx / K;
    int r = idx - co * K;
    int tap = r / Cin, ci = r - tap * Cin;
    Bh[idx] = (_Float16)w[((size_t)co * Cin + ci) * 9 + tap];
}

// C[m][c] = bias[c], over M*N elements (N pow2)
__global__ __launch_bounds__(TPB) void bias_mc_k(float* __restrict__ C,
                                                 const float* __restrict__ bias,
                                                 int mask) {
    int idx = blockIdx.x * TPB + threadIdx.x;
    C[idx] = bias[idx & mask];
}

// X[m][ci] fp16  <-  W4 spatial [b,ci,16,16] fp32
__global__ __launch_bounds__(TPB) void w4_to_x_k(const float* __restrict__ W4,
                                                 _Float16* __restrict__ X) {
    int idx = blockIdx.x * TPB + threadIdx.x;   // over 1M
    int m = idx >> 10, ci = idx & 1023;
    int b = m >> 8, p = m & 255;
    X[idx] = (_Float16)W4[(((size_t)b << 10) + ci) * 256 + p];
}

// Fused implicit-im2col GEMM.
// C[m][n] += sum_k A[m][k]*Bw[n][k], A[m][tap*CIN+ci] = X[nbr(m,tap)][ci] or 0.
// LC = log2(CIN); NT: block n-tile = NT*32 (NT=4 ->128, NT=2 ->64).
// grid: (M/128, N/(NT*32), KS); kc = K/KS (multiple of 32).
template <int LC, int NT>
__global__ __launch_bounds__(TPB) void cgemm_k(
    const _Float16* __restrict__ X,
    const _Float16* __restrict__ Bw,
    float* __restrict__ Cout,
    int Wimg, int kc, int N) {
    constexpr int CIN = 1 << LC;
    constexpr int K = 9 << LC;
    const int HW = Wimg * Wimg;
    const int m0 = blockIdx.x * 128;
    const int n0 = blockIdx.y * (NT * 32);
    const int k0 = blockIdx.z * kc;
    const int iters = kc >> 5;

    __shared__ _Float16 As[128 * 32];
    __shared__ _Float16 Bs[NT * 32 * 32];

    const int tid = threadIdx.x;
    const int wave = tid >> 6, lane = tid & 63;
    const int wm = (wave >> 1) * 64;
    const int wn = (wave & 1) * (NT * 16);

    // A staging geometry: rows r0=tid>>2 and r0+64, 8 halfs at colh
    const int r0 = tid >> 2;
    const int colh = (tid & 3) * 8;
    int rbase[2], rh[2], rw[2];
#pragma unroll
    for (int q = 0; q < 2; q++) {
        int m = m0 + r0 + q * 64;
        int b = m / HW;
        int p = m - b * HW;
        rh[q] = p / Wimg;
        rw[q] = p - rh[q] * Wimg;
        rbase[q] = b * HW;
    }
    _Float16* lA0 = &As[r0 * 32 + colh];
    _Float16* lA1 = &As[(r0 + 64) * 32 + colh];

    // B staging: NT/2 chunks of 4 KB via global_load_lds
    const int f = tid * 16;
    const int brow = f >> 6, bbyte = f & 63;
    const char* gB[NT / 2];
#pragma unroll
    for (int q = 0; q < NT / 2; q++)
        gB[q] = (const char*)Bw + ((size_t)(n0 + brow + q * 64) * K + k0) * 2 + bbyte;

    f32x4 acc[4][NT];
#pragma unroll
    for (int i = 0; i < 4; i++)
#pragma unroll
        for (int j = 0; j < NT; j++) acc[i][j] = {0.f, 0.f, 0.f, 0.f};

    const int frow = lane & 15;
    const int fkh = (lane >> 4) * 8;

    for (int it = 0; it < iters; ++it) {
        const int kk = k0 + (it << 5);
        const int tap = kk >> LC;
        const int ci0 = kk & (CIN - 1);
        const int t3 = tap / 3;
        const int dh = t3 - 1;
        const int dw = tap - t3 * 3 - 1;
#pragma unroll
        for (int q = 0; q < 2; q++) {
            int hh = rh[q] + dh, ww = rw[q] + dw;
            f16x8 v = {0, 0, 0, 0, 0, 0, 0, 0};
            if ((unsigned)hh < (unsigned)Wimg && (unsigned)ww < (unsigned)Wimg)
                v = *(const f16x8*)(X + (((size_t)(rbase[q] + hh * Wimg + ww)) << LC)
                                      + ci0 + colh);
            if (q == 0) *(f16x8*)lA0 = v;
            else        *(f16x8*)lA1 = v;
        }
#pragma unroll
        for (int q = 0; q < NT / 2; q++) {
            GLOAD_LDS16(gB[q], (char*)Bs + f + q * 4096);
            gB[q] += 64;
        }
        __syncthreads();

        f16x8 af[4], bf[NT];
#pragma unroll
        for (int mt = 0; mt < 4; mt++)
            af[mt] = *(const f16x8*)&As[(wm + mt * 16 + frow) * 32 + fkh];
#pragma unroll
        for (int nt = 0; nt < NT; nt++)
            bf[nt] = *(const f16x8*)&Bs[(wn + nt * 16 + frow) * 32 + fkh];
#pragma unroll
        for (int mt = 0; mt < 4; mt++)
#pragma unroll
            for (int nt = 0; nt < NT; nt++)
                acc[mt][nt] = __builtin_amdgcn_mfma_f32_16x16x32_f16(
                    af[mt], bf[nt], acc[mt][nt], 0, 0, 0);
        __syncthreads();
    }

    // epilogue: C/D layout col = lane&15, row = (lane>>4)*4 + reg
    const int cm = m0 + wm + (lane >> 4) * 4;
    const int cn = n0 + wn + (lane & 15);
#pragma unroll
    for (int mt = 0; mt < 4; mt++)
#pragma unroll
        for (int nt = 0; nt < NT; nt++)
#pragma unroll
            for (int r = 0; r < 4; r++)
                unsafeAtomicAdd(&Cout[(size_t)(cm + mt * 16 + r) * N + cn + nt * 16],
                                acc[mt][nt][r]);
}

// lrelu finalize from C[m][N]: optional spatial fp32 + optional channels-last fp16.
// LN = log2 N, LHW = log2 HW. Over M*N elements.
template <bool SPAT, bool CL>
__global__ __launch_bounds__(TPB) void fin_cl_k(const float* __restrict__ Cm,
                                                float* __restrict__ spat,
                                                _Float16* __restrict__ X,
                                                int LN, int LHW, int Coff, int Ctot) {
    int idx = blockIdx.x * TPB + threadIdx.x;
    int m = idx >> LN;
    int c = idx & ((1 << LN) - 1);
    float v = Cm[idx];
    v = (v >= 0.0f) ? v : 0.2f * v;
    if (SPAT) {
        int b = m >> LHW;
        int p = m & ((1 << LHW) - 1);
        spat[(((size_t)(b << LN) + c) << LHW) + p] = v;
    }
    if (CL) X[(size_t)m * Ctot + Coff + c] = (_Float16)v;
}

// conv4 step-10 finalize: spatial out = lrelu(C[m][1024] + W4 spatial)
__global__ __launch_bounds__(TPB) void fin_sp_k(const float* __restrict__ C,
                                                const float* __restrict__ W4,
                                                float* __restrict__ out) {
    int idx = blockIdx.x * TPB + threadIdx.x;   // over 1M, (b,c,p)
    int b = idx >> 18;
    int r = idx & 262143;
    int c = r >> 8, p = r & 255;
    int m = (b << 8) + p;
    float v = C[(size_t)m * 1024 + c] + W4[idx];
    out[idx] = (v >= 0.0f) ? v : 0.2f * v;
}

// Fused final iwt (12ch -> 3ch, 128->256) + 1x1 conv (3->3, no bias).
__global__ __launch_bounds__(TPB) void final_k(const float* __restrict__ src,
                                               const float* __restrict__ cf,
                                               float* __restrict__ out) {
    int p = blockIdx.x * TPB + threadIdx.x;
    int b = blockIdx.z;
    int h = p >> 7, w = p & 127;
    const int st = 128 * 128;
    float y00[3], y01[3], y10[3], y11[3];
    const float* r = src + (size_t)b * 12 * st + p;
#pragma unroll
    for (int c = 0; c < 3; c++) {
        float v0 = r[(4 * c) * st];
        float v1 = 2.0f * r[(4 * c + 1) * st] - 1.0f;
        float v2 = 2.0f * r[(4 * c + 2) * st] - 1.0f;
        float v3 = 2.0f * r[(4 * c + 3) * st] - 1.0f;
        y00[c] = v0 + 0.5f * ( v1 + v2 + v3);
        y01[c] = v0 + 0.5f * ( v1 - v2 - v3);
        y10[c] = v0 + 0.5f * (-v1 + v2 - v3);
        y11[c] = v0 + 0.5f * (-v1 - v2 + v3);
    }
#pragma unroll
    for (int o = 0; o < 3; o++) {
        float k0 = cf[o * 3], k1 = cf[o * 3 + 1], k2 = cf[o * 3 + 2];
        float* q = out + (((size_t)b * 3 + o) * 256 + 2 * h) * 256 + 2 * w;
        q[0]   = k0 * y00[0] + k1 * y00[1] + k2 * y00[2];
        q[1]   = k0 * y01[0] + k1 * y01[1] + k2 * y01[2];
        q[256] = k0 * y10[0] + k1 * y10[1] + k2 * y10[2];
        q[257] = k0 * y11[0] + k1 * y11[1] + k2 * y11[2];
    }
}

static inline void conv_launch(const float* s0, int C0, const float* s1,
                               const float* wgt, const float* bias,
                               float* out, int Cin, int Cout, int H, int W,
                               int CO, hipStream_t st) {
    dim3 grid((H * W + TPB - 1) / TPB, Cout / CO, 4);
    if (CO == 8)
        conv3x3_k<8, true, false><<<grid, TPB, 0, st>>>(s0, C0, s1, wgt, bias, nullptr, out, Cin, Cout, H, W);
    else
        conv3x3_k<4, true, false><<<grid, TPB, 0, st>>>(s0, C0, s1, wgt, bias, nullptr, out, Cin, Cout, H, W);
}

extern "C" void kernel_launch(void* const* d_in, const int* in_sizes, int n_in,
                              void* d_out, int out_size, void* d_ws, size_t ws_size,
                              hipStream_t stream) {
    (void)in_sizes; (void)n_in; (void)out_size; (void)ws_size;
    const float* x      = (const float*)d_in[0];
    const float* c1w    = (const float*)d_in[1];
    const float* c1b    = (const float*)d_in[2];
    const float* c2w    = (const float*)d_in[3];
    const float* c2b    = (const float*)d_in[4];
    const float* c3w    = (const float*)d_in[5];
    const float* c3b    = (const float*)d_in[6];
    const float* c4w    = (const float*)d_in[7];
    const float* c4b    = (const float*)d_in[8];
    const float* d4w    = (const float*)d_in[9];
    const float* d4b    = (const float*)d_in[10];
    const float* d3w    = (const float*)d_in[11];
    const float* d3b    = (const float*)d_in[12];
    const float* d2w    = (const float*)d_in[13];
    const float* d2b    = (const float*)d_in[14];
    const float* d1w    = (const float*)d_in[15];
    const float* d1b    = (const float*)d_in[16];
    const float* cfin   = (const float*)d_in[17];
    float* out = (float*)d_out;

    char* base = (char*)d_ws;
    const size_t MB = 1 << 20;
    float*    C1   = (float*)(base + 0 * MB);     // (4,16,128,128)
    float*    C3   = (float*)(base + 4 * MB);     // (4,256,32,32)
    float*    W4   = (float*)(base + 8 * MB);     // (4,1024,16,16)
    float*    TA   = (float*)(base + 12 * MB);
    float*    TB   = (float*)(base + 16 * MB);
    float*    C2   = (float*)(base + 20 * MB);    // (4,64,64,64)
    float*    Cmc  = (float*)(base + 24 * MB);    // GEMM acc, 1M floats
    _Float16* X0   = (_Float16*)(base + 28 * MB); // [1024][1024]
    _Float16* X1   = (_Float16*)(base + 30 * MB);
    _Float16* Xa   = (_Float16*)(base + 32 * MB); // w2 [16384][64] / w3 [4096][256]
    _Float16* Xd3  = (_Float16*)(base + 34 * MB); // [16384][128] concat(c2,t3)
    _Float16* Xd4  = (_Float16*)(base + 38 * MB); // [4096][512]  concat(c3,t4)
    _Float16* Bh4  = (_Float16*)(base + 42 * MB); // [1024][9216] 18 MiB
    _Float16* Bh3  = (_Float16*)(base + 60 * MB); // [256][2304]
    _Float16* Bhd4 = (_Float16*)(base + 62 * MB); // [256][4608]
    _Float16* Bhd3 = (_Float16*)(base + 65 * MB); // [64][1152]
    _Float16* Bh2  = (_Float16*)(base + 66 * MB); // [64][576]

    // weight transforms (every call; graph-safe). n = Cout*9*Cin, grid = n/256.
    wtrans_g_k<<<36864, TPB, 0, stream>>>(c4w, Bh4, 1024, 9437184);
    wtrans_g_k<<<2304,  TPB, 0, stream>>>(c3w, Bh3, 256, 589824);
    wtrans_g_k<<<4608,  TPB, 0, stream>>>(d4w, Bhd4, 512, 1179648);   // FIXED (was 2x)
    wtrans_g_k<<<288,   TPB, 0, stream>>>(d3w, Bhd3, 128, 73728);
    wtrans_g_k<<<144,   TPB, 0, stream>>>(c2w, Bh2, 64, 36864);

    // 1. w1 = wt(x): (4,3,256,256) -> (4,12,128,128) spatial, in TA
    wt_k<<<dim3(192, 1, 4), TPB, 0, stream>>>(x, TA, 3, 128, 128);
    // 2. c1 = lrelu(conv1(w1)): 12 -> 16 @128^2 (generic)
    conv_launch(TA, 12, nullptr, c1w, c1b, C1, 12, 16, 128, 128, 8, stream);
    // 3. w2 = wt(c1) -> channels-last Xa [16384][64]
    wt_cl_k<4><<<dim3(256, 1, 4), TPB, 0, stream>>>(C1, Xa, 64, 64);
    // 4. c2 = lrelu(conv2(w2)): GEMM M=16384 N=64 K=576 -> C2 spatial + Xd3[:,0:64]
    bias_mc_k<<<4096, TPB, 0, stream>>>(Cmc, c2b, 63);
    cgemm_k<6, 2><<<dim3(128, 1, 2), TPB, 0, stream>>>(Xa, Bh2, Cmc, 64, 288, 64);
    fin_cl_k<true, true><<<4096, TPB, 0, stream>>>(Cmc, C2, Xd3, 6, 12, 0, 128);
    // 5. w3 = wt(c2) -> channels-last Xa [4096][256]
    wt_cl_k<6><<<dim3(256, 1, 4), TPB, 0, stream>>>(C2, Xa, 32, 32);
    // 6. c3 = lrelu(conv3(w3)): GEMM M=4096 N=256 K=2304 -> C3 spatial + Xd4[:,0:256]
    bias_mc_k<<<4096, TPB, 0, stream>>>(Cmc, c3b, 255);
    cgemm_k<8, 4><<<dim3(32, 2, 4), TPB, 0, stream>>>(Xa, Bh3, Cmc, 32, 576, 256);
    fin_cl_k<true, true><<<4096, TPB, 0, stream>>>(Cmc, C3, Xd4, 8, 10, 0, 512);
    // 7. w4 = wt(c3) -> W4 spatial (skip) + X0 channels-last
    wt_k<<<dim3(256, 1, 4), TPB, 0, stream>>>(C3, W4, 256, 16, 16);
    w4_to_x_k<<<4096, TPB, 0, stream>>>(W4, X0);
    // 8. c4 = lrelu(conv4(w4)) -> X1
    bias_mc_k<<<4096, TPB, 0, stream>>>(Cmc, c4b, 1023);
    cgemm_k<10, 4><<<dim3(8, 8, 8), TPB, 0, stream>>>(X0, Bh4, Cmc, 16, 1152, 1024);
    fin_cl_k<false, true><<<4096, TPB, 0, stream>>>(Cmc, nullptr, X1, 10, 8, 0, 1024);
    // 9. c5 = lrelu(conv4(c4)) -> X0
    bias_mc_k<<<4096, TPB, 0, stream>>>(Cmc, c4b, 1023);
    cgemm_k<10, 4><<<dim3(8, 8, 8), TPB, 0, stream>>>(X1, Bh4, Cmc, 16, 1152, 1024);
    fin_cl_k<false, true><<<4096, TPB, 0, stream>>>(Cmc, nullptr, X0, 10, 8, 0, 1024);
    // 10. ic4 = lrelu(conv4(c5) + w4) -> TA spatial
    bias_mc_k<<<4096, TPB, 0, stream>>>(Cmc, c4b, 1023);
    cgemm_k<10, 4><<<dim3(8, 8, 8), TPB, 0, stream>>>(X0, Bh4, Cmc, 16, 1152, 1024);
    fin_sp_k<<<4096, TPB, 0, stream>>>(Cmc, W4, TA);
    // 11. t4 = iwt(ic4) -> Xd4[:,256:512]
    iwt_cl_k<8><<<dim3(256, 1, 4), TPB, 0, stream>>>(TA, Xd4, 16, 16, 256, 512);
    // 12. ic3 = lrelu(convd4(c3||t4)): GEMM M=4096 N=256 K=4608 -> TA spatial
    bias_mc_k<<<4096, TPB, 0, stream>>>(Cmc, d4b, 255);
    cgemm_k<9, 4><<<dim3(32, 2, 4), TPB, 0, stream>>>(Xd4, Bhd4, Cmc, 32, 1152, 256);
    fin_cl_k<true, false><<<4096, TPB, 0, stream>>>(Cmc, TA, nullptr, 8, 10, 0, 0);
    // 13. t3 = iwt(ic3) -> Xd3[:,64:128]
    iwt_cl_k<6><<<dim3(256, 1, 4), TPB, 0, stream>>>(TA, Xd3, 32, 32, 64, 128);
    // 14. ic2 = lrelu(convd3(c2||t3)): GEMM M=16384 N=64 K=1152 -> TA spatial
    bias_mc_k<<<4096, TPB, 0, stream>>>(Cmc, d3b, 63);
    cgemm_k<7, 2><<<dim3(128, 1, 2), TPB, 0, stream>>>(Xd3, Bhd3, Cmc, 64, 576, 64);
    fin_cl_k<true, false><<<4096, TPB, 0, stream>>>(Cmc, TA, nullptr, 6, 12, 0, 0);
    // 15. t2 = iwt(ic2) -> TB spatial (4,16,128,128)
    iwt_k<<<dim3(256, 1, 4), TPB, 0, stream>>>(TA, TB, 16, 64, 64);
    // 16. ic1 = lrelu(convd2(c1||t2)): 32 -> 16 @128^2 (generic) -> TA
    conv_launch(C1, 16, TB, d2w, d2b, TA, 32, 16, 128, 128, 8, stream);
    // 17. iw1 = lrelu(convd1(ic1)): 16 -> 12 @128^2 (generic) -> TB
    conv_launch(TA, 16, TA, d1w, d1b, TB, 16, 12, 128, 128, 4, stream);
    // 18. out = 1x1(iwt(iw1)) fused
    final_k<<<dim3(64, 1, 4), TPB, 0, stream>>>(TB, cfin, out);
}

// Round 7
// 608.935 us; speedup vs baseline: 8.7639x; 1.0489x over previous
//
#include <hip/hip_runtime.h>

// ---------------------------------------------------------------------------
// Waveletnet: Haar DWT U-Net.
// R7: pipelined conflict-free cgemm.
//  - LDS in fragment-tile order: 16(m/n) x 32(k) MFMA tile stored as
//    [lane 0..63][16B], so all ds_read_b128 / ds_write_b128 are sequential
//    (zero bank conflicts). B weights pre-swizzled in wtrans_sw_k so
//    global_load_lds streams land directly in fragment order.
//  - Double-buffered single-barrier K-loop: B-DMA + A-reg loads for it+1
//    issue before it's MFMAs, ds_write after, one barrier per iter.
//  - K-splits raised: all GEMMs >= 384 blocks.
//  - fin kernels chain-write next layer's bias into Cmc (per-element RMW);
//    wt_dual fuses W4 spatial + channels-last emit. 7 dispatches saved.
// Small layers (conv1, convd2, convd1) stay on the generic fp32 kernel.
// ---------------------------------------------------------------------------

#define TPB 256

typedef _Float16 f16x8 __attribute__((ext_vector_type(8)));
typedef float f32x4 __attribute__((ext_vector_type(4)));

#define GLOAD_LDS16(g, l)                                                     \
    __builtin_amdgcn_global_load_lds(                                         \
        (const __attribute__((address_space(1))) void*)(g),                   \
        (__attribute__((address_space(3))) void*)(l), 16, 0, 0)

// ---- spatial wt (fp32 -> fp32) --------------------------------------------
__global__ __launch_bounds__(TPB) void wt_k(const float* __restrict__ src,
                                            float* __restrict__ dst,
                                            int C, int H2, int W2) {
    int n = C * H2 * W2;
    int idx = blockIdx.x * TPB + threadIdx.x;
    if (idx >= n) return;
    int b = blockIdx.z;
    int c = idx / (H2 * W2);
    int p = idx - c * (H2 * W2);
    int h = p / W2, w = p - h * W2;
    int W = 2 * W2;
    const float* r = src + (((size_t)b * C + c) * (2 * H2) + 2 * h) * W + 2 * w;
    float a = r[0], bb = r[1], cc = r[W], dd = r[W + 1];
    size_t st = (size_t)H2 * W2;
    float* o = dst + (((size_t)b * 4 * C + 4 * c) * st) + p;
    o[0]      = 0.25f * (a + bb + cc + dd);
    o[st]     = (0.5f * (a + bb - cc - dd) + 1.0f) * 0.5f;
    o[2 * st] = (0.5f * (a - bb + cc - dd) + 1.0f) * 0.5f;
    o[3 * st] = (0.5f * (a - bb - cc + dd) + 1.0f) * 0.5f;
}

// ---- wt for step 7: spatial fp32 out (skip) + channels-last fp16 out -------
// C=256, H2=W2=16. idx over 256ch*256px.
__global__ __launch_bounds__(TPB) void wt_dual_k(const float* __restrict__ src,
                                                 float* __restrict__ dst,
                                                 _Float16* __restrict__ X) {
    int idx = blockIdx.x * TPB + threadIdx.x;
    int b = blockIdx.z;
    int c = idx >> 8;
    int p = idx & 255;
    int h = p >> 4, w = p & 15;
    const float* r = src + (((size_t)b * 256 + c) * 32 + 2 * h) * 32 + 2 * w;
    float a = r[0], bb = r[1], cc = r[32], dd = r[33];
    float v0 = 0.25f * (a + bb + cc + dd);
    float v1 = (0.5f * (a + bb - cc - dd) + 1.0f) * 0.5f;
    float v2 = (0.5f * (a - bb + cc - dd) + 1.0f) * 0.5f;
    float v3 = (0.5f * (a - bb - cc + dd) + 1.0f) * 0.5f;
    float* o = dst + (((size_t)b * 1024 + 4 * c) * 256) + p;
    o[0] = v0; o[256] = v1; o[512] = v2; o[768] = v3;
    _Float16* q = X + ((size_t)(b * 256 + p)) * 1024 + 4 * c;
    q[0] = (_Float16)v0; q[1] = (_Float16)v1;
    q[2] = (_Float16)v2; q[3] = (_Float16)v3;
}

// ---- wt: spatial fp32 in -> channels-last fp16 out -------------------------
template <int LC>
__global__ __launch_bounds__(TPB) void wt_cl_k(const float* __restrict__ src,
                                               _Float16* __restrict__ X,
                                               int H2, int W2) {
    const int C = 1 << LC;
    int idx = blockIdx.x * TPB + threadIdx.x;
    int b = blockIdx.z;
    int c = idx & (C - 1);
    int p = idx >> LC;
    if (p >= H2 * W2) return;
    int h = p / W2, w = p - h * W2;
    int W = 2 * W2;
    const float* r = src + (((size_t)b * C + c) * (2 * H2) + 2 * h) * W + 2 * w;
    float a = r[0], bb = r[1], cc = r[W], dd = r[W + 1];
    _Float16* o = X + ((size_t)(b * H2 * W2 + p)) * (4 * C) + 4 * c;
    o[0] = (_Float16)(0.25f * (a + bb + cc + dd));
    o[1] = (_Float16)((0.5f * (a + bb - cc - dd) + 1.0f) * 0.5f);
    o[2] = (_Float16)((0.5f * (a - bb + cc - dd) + 1.0f) * 0.5f);
    o[3] = (_Float16)((0.5f * (a - bb - cc + dd) + 1.0f) * 0.5f);
}

// ---- spatial iwt (fp32 -> fp32) -------------------------------------------
__global__ __launch_bounds__(TPB) void iwt_k(const float* __restrict__ src,
                                             float* __restrict__ dst,
                                             int C, int H, int W) {
    int n = C * H * W;
    int idx = blockIdx.x * TPB + threadIdx.x;
    if (idx >= n) return;
    int b = blockIdx.z;
    int c = idx / (H * W);
    int p = idx - c * (H * W);
    int h = p / W, w = p - h * W;
    size_t st = (size_t)H * W;
    const float* r = src + ((size_t)b * 4 * C + 4 * c) * st + p;
    float v0 = r[0];
    float v1 = 2.0f * r[st] - 1.0f;
    float v2 = 2.0f * r[2 * st] - 1.0f;
    float v3 = 2.0f * r[3 * st] - 1.0f;
    float* o = dst + (((size_t)b * C + c) * (2 * H) + 2 * h) * (2 * W) + 2 * w;
    o[0]         = v0 + 0.5f * ( v1 + v2 + v3);
    o[1]         = v0 + 0.5f * ( v1 - v2 - v3);
    o[2 * W]     = v0 + 0.5f * (-v1 + v2 - v3);
    o[2 * W + 1] = v0 + 0.5f * (-v1 - v2 + v3);
}

// ---- iwt: spatial fp32 in -> channels-last fp16 (into concat slice) --------
template <int LC>
__global__ __launch_bounds__(TPB) void iwt_cl_k(const float* __restrict__ src,
                                                _Float16* __restrict__ X,
                                                int H, int W, int Coff, int Ctot) {
    const int C = 1 << LC;
    int idx = blockIdx.x * TPB + threadIdx.x;
    int b = blockIdx.z;
    int c = idx & (C - 1);
    int p = idx >> LC;
    if (p >= H * W) return;
    int h = p / W, w = p - h * W;
    size_t st = (size_t)H * W;
    const float* r = src + ((size_t)b * 4 * C + 4 * c) * st + p;
    float v0 = r[0];
    float v1 = 2.0f * r[st] - 1.0f;
    float v2 = 2.0f * r[2 * st] - 1.0f;
    float v3 = 2.0f * r[3 * st] - 1.0f;
    size_t mb = (size_t)b * 4 * H * W + (size_t)(2 * h) * (2 * W) + 2 * w;
    _Float16* o = X + mb * Ctot + Coff + c;
    o[0]                          = (_Float16)(v0 + 0.5f * ( v1 + v2 + v3));
    o[(size_t)Ctot]               = (_Float16)(v0 + 0.5f * ( v1 - v2 - v3));
    o[(size_t)(2 * W) * Ctot]     = (_Float16)(v0 + 0.5f * (-v1 + v2 - v3));
    o[(size_t)(2 * W + 1) * Ctot] = (_Float16)(v0 + 0.5f * (-v1 - v2 + v3));
}

// ---- generic direct 3x3 conv (conv1, convd2, convd1) -----------------------
template <int CO, bool LRELU, bool HAS_SKIP>
__global__ __launch_bounds__(TPB) void conv3x3_k(
    const float* __restrict__ s0, int C0,
    const float* __restrict__ s1,
    const float* __restrict__ wgt, const float* __restrict__ bias,
    const float* __restrict__ skip,
    float* __restrict__ out,
    int Cin, int Cout, int H, int W) {
    const int hw = H * W;
    int p = blockIdx.x * TPB + threadIdx.x;
    if (p >= hw) return;
    const int b = blockIdx.z;
    const int cog = blockIdx.y * CO;
    const int h = p / W, w = p - (p / W) * W;
    const bool hm = h > 0, hp = h < H - 1, wm = w > 0, wpp = w < W - 1;

    float acc[CO];
#pragma unroll
    for (int i = 0; i < CO; i++) acc[i] = bias[cog + i];

    const int C1n = Cin - C0;
    for (int ci = 0; ci < Cin; ci++) {
        const float* sp = (ci < C0)
            ? s0 + ((size_t)b * C0 + ci) * hw
            : s1 + ((size_t)b * C1n + (ci - C0)) * hw;
        const float* r = sp + p;
        float x00 = (hm && wm)  ? r[-W - 1] : 0.0f;
        float x01 = hm          ? r[-W]     : 0.0f;
        float x02 = (hm && wpp) ? r[-W + 1] : 0.0f;
        float x10 = wm          ? r[-1]     : 0.0f;
        float x11 =               r[0];
        float x12 = wpp         ? r[1]      : 0.0f;
        float x20 = (hp && wm)  ? r[W - 1]  : 0.0f;
        float x21 = hp          ? r[W]      : 0.0f;
        float x22 = (hp && wpp) ? r[W + 1]  : 0.0f;
        const float* wk = wgt + ((size_t)cog * Cin + ci) * 9;
#pragma unroll
        for (int i = 0; i < CO; i++) {
            const float* wi = wk + (size_t)i * Cin * 9;
            acc[i] += x00 * wi[0] + x01 * wi[1] + x02 * wi[2]
                    + x10 * wi[3] + x11 * wi[4] + x12 * wi[5]
                    + x20 * wi[6] + x21 * wi[7] + x22 * wi[8];
        }
    }
#pragma unroll
    for (int i = 0; i < CO; i++) {
        float v = acc[i];
        if (HAS_SKIP) v += skip[((size_t)b * Cout + cog + i) * hw + p];
        if (LRELU) v = (v >= 0.0f) ? v : 0.2f * v;
        out[((size_t)b * Cout + cog + i) * hw + p] = v;
    }
}

// ---- MFMA GEMM path --------------------------------------------------------

// Swizzled weight transform. Bh layout: chunks of 4KB = (nb64, kb32):
//   chunk index = nb*(Kd/32)+kb; inside: [sub 0..3][lane 0..63][8 halfs]
//   where co = nb*64 + sub*16 + (lane&15), k = kb*32 + ((lane>>4)&3)*8 + e.
// Dst-linear (coalesced writes), gathered reads from w[co][ci][tap].
__global__ __launch_bounds__(TPB) void wtrans_sw_k(const float* __restrict__ w,
                                                   _Float16* __restrict__ Bh,
                                                   int Cin, int KB, int n) {
    int idx = blockIdx.x * TPB + threadIdx.x;
    if (idx >= n) return;
    int e = idx & 7;
    int lane = (idx >> 3) & 63;
    int sub = (idx >> 9) & 3;
    int chunk = idx >> 11;
    int kb = chunk % KB;
    int nb = chunk / KB;
    int co = nb * 64 + sub * 16 + (lane & 15);
    int k = kb * 32 + ((lane >> 4) & 3) * 8 + e;
    int tap = k / Cin;
    int ci = k - tap * Cin;
    Bh[idx] = (_Float16)w[((size_t)co * Cin + ci) * 9 + tap];
}

// C[m][c] = bias[c] (initial seed for first GEMM only)
__global__ __launch_bounds__(TPB) void bias_mc_k(float* __restrict__ C,
                                                 const float* __restrict__ bias,
                                                 int mask) {
    int idx = blockIdx.x * TPB + threadIdx.x;
    C[idx] = bias[idx & mask];
}

// Pipelined, conflict-free fused implicit-im2col GEMM.
// C[m][n] += sum_k A[m][k]*Bw[n][k]; A built on the fly from channels-last X.
// LC = log2(CIN); NT in {2,4}: block n-tile = NT*32.
// grid (M/128, N/(NT*32), KS); kc = K/KS, multiple of 32.
template <int LC, int NT>
__global__ __launch_bounds__(TPB) void cgemm_k(
    const _Float16* __restrict__ X,
    const _Float16* __restrict__ Bw,   // swizzled (wtrans_sw_k layout)
    float* __restrict__ Cout,
    int Wimg, int kc, int N) {
    constexpr int CIN = 1 << LC;
    constexpr int Kd = 9 << LC;
    constexpr int KB = Kd >> 5;
    const int HW = Wimg * Wimg;
    const int m0 = blockIdx.x * 128;
    const int n0 = blockIdx.y * (NT * 32);
    const int k0 = blockIdx.z * kc;
    const int iters = kc >> 5;

    __shared__ _Float16 As[2][4096];
    __shared__ _Float16 Bs[2][NT * 1024];

    const int tid = threadIdx.x;
    const int wave = tid >> 6, lane = tid & 63;
    const int wm = (wave >> 1) * 64;
    const int wn = (wave & 1) * (NT * 16);

    // A staging slots: q=0 -> addr16=tid, q=1 -> addr16=tid+256.
    // decode: tile t = a16>>6, slot l = a16&63; row=t*16+(l&15), colh=((l>>4)&3)*8
    int rh[2], rw[2], rbase[2], cq[2];
#pragma unroll
    for (int q = 0; q < 2; q++) {
        int a16 = tid + q * 256;
        int t = a16 >> 6, l = a16 & 63;
        int row = t * 16 + (l & 15);
        cq[q] = ((l >> 4) & 3) * 8;
        int m = m0 + row;
        int b = m / HW;
        int p = m - b * HW;
        rh[q] = p / Wimg;
        rw[q] = p - rh[q] * Wimg;
        rbase[q] = b * HW;
    }

    const int nb0 = n0 >> 6;
    const int kb0 = k0 >> 5;

#define STAGE_B(it, dbuf)                                                       \
    {                                                                           \
        int kb = kb0 + (it);                                                    \
        const char* g0 = (const char*)Bw +                                      \
            ((size_t)(nb0 * KB + kb) * 2048 + (size_t)tid * 8) * 2;             \
        GLOAD_LDS16(g0, (char*)&Bs[dbuf][0] + tid * 16);                        \
        if (NT == 4) {                                                          \
            const char* g1 = (const char*)Bw +                                  \
                ((size_t)((nb0 + 1) * KB + kb) * 2048 + (size_t)tid * 8) * 2;   \
            GLOAD_LDS16(g1, (char*)&Bs[dbuf][2048] + tid * 16);                 \
        }                                                                       \
    }

#define LOAD_A(it, a0v, a1v)                                                    \
    {                                                                           \
        const int kk = k0 + ((it) << 5);                                        \
        const int tap = kk >> LC;                                               \
        const int ci0 = kk & (CIN - 1);                                         \
        const int t3 = tap / 3;                                                 \
        const int dh = t3 - 1, dwv = tap - t3 * 3 - 1;                          \
        int hh0 = rh[0] + dh, ww0 = rw[0] + dwv;                                \
        a0v = (f16x8){0, 0, 0, 0, 0, 0, 0, 0};                                  \
        if ((unsigned)hh0 < (unsigned)Wimg && (unsigned)ww0 < (unsigned)Wimg)   \
            a0v = *(const f16x8*)(X +                                           \
                (((size_t)(rbase[0] + hh0 * Wimg + ww0)) << LC) + ci0 + cq[0]); \
        int hh1 = rh[1] + dh, ww1 = rw[1] + dwv;                                \
        a1v = (f16x8){0, 0, 0, 0, 0, 0, 0, 0};                                  \
        if ((unsigned)hh1 < (unsigned)Wimg && (unsigned)ww1 < (unsigned)Wimg)   \
            a1v = *(const f16x8*)(X +                                           \
                (((size_t)(rbase[1] + hh1 * Wimg + ww1)) << LC) + ci0 + cq[1]); \
    }

    f32x4 acc[4][NT];
#pragma unroll
    for (int i = 0; i < 4; i++)
#pragma unroll
        for (int j = 0; j < NT; j++) acc[i][j] = {0.f, 0.f, 0.f, 0.f};

    f16x8 a0, a1;
    // prologue: stage iter 0
    STAGE_B(0, 0);
    LOAD_A(0, a0, a1);
    *(f16x8*)&As[0][(size_t)tid * 8] = a0;
    *(f16x8*)&As[0][(size_t)(tid + 256) * 8] = a1;
    __syncthreads();

    int buf = 0;
    for (int it = 0; it < iters; ++it) {
        const bool more = (it + 1) < iters;
        if (more) {
            STAGE_B(it + 1, buf ^ 1);     // DMA in flight across compute
            LOAD_A(it + 1, a0, a1);       // global->VGPR in flight
        }
        f16x8 af[4], bf[NT];
#pragma unroll
        for (int mt = 0; mt < 4; mt++)
            af[mt] = *(const f16x8*)&As[buf][((wm >> 4) + mt) * 512 + lane * 8];
#pragma unroll
        for (int nt = 0; nt < NT; nt++)
            bf[nt] = *(const f16x8*)&Bs[buf][((wn >> 4) + nt) * 512 + lane * 8];
#pragma unroll
        for (int mt = 0; mt < 4; mt++)
#pragma unroll
            for (int nt = 0; nt < NT; nt++)
                acc[mt][nt] = __builtin_amdgcn_mfma_f32_16x16x32_f16(
                    af[mt], bf[nt], acc[mt][nt], 0, 0, 0);
        if (more) {
            *(f16x8*)&As[buf ^ 1][(size_t)tid * 8] = a0;
            *(f16x8*)&As[buf ^ 1][(size_t)(tid + 256) * 8] = a1;
        }
        __syncthreads();
        buf ^= 1;
    }
#undef STAGE_B
#undef LOAD_A

    // epilogue: C/D layout col = lane&15, row = (lane>>4)*4 + reg
    const int cm = m0 + wm + (lane >> 4) * 4;
    const int cn = n0 + wn + (lane & 15);
#pragma unroll
    for (int mt = 0; mt < 4; mt++)
#pragma unroll
        for (int nt = 0; nt < NT; nt++)
#pragma unroll
            for (int r = 0; r < 4; r++)
                unsafeAtomicAdd(&Cout[(size_t)(cm + mt * 16 + r) * N + cn + nt * 16],
                                acc[mt][nt][r]);
}

// lrelu finalize from Cm[m][N]; optional spatial fp32, channels-last fp16,
// and next-layer bias chain write (per-element RMW at the read position).
template <bool SPAT, bool CL, bool NB>
__global__ __launch_bounds__(TPB) void fin_cl_k(float* __restrict__ Cm,
                                                float* __restrict__ spat,
                                                _Float16* __restrict__ X,
                                                int LN, int LHW, int Coff, int Ctot,
                                                const float* __restrict__ nbias,
                                                int nmask) {
    int idx = blockIdx.x * TPB + threadIdx.x;
    int m = idx >> LN;
    int c = idx & ((1 << LN) - 1);
    float v = Cm[idx];
    v = (v >= 0.0f) ? v : 0.2f * v;
    if (SPAT) {
        int b = m >> LHW;
        int p = m & ((1 << LHW) - 1);
        spat[(((size_t)(b << LN) + c) << LHW) + p] = v;
    }
    if (CL) X[(size_t)m * Ctot + Coff + c] = (_Float16)v;
    if (NB) Cm[idx] = nbias[idx & nmask];
}

// conv4 step-10 finalize: spatial out = lrelu(Cm[m][1024] + W4), + bias chain
template <bool NB>
__global__ __launch_bounds__(TPB) void fin_sp_k(float* __restrict__ Cm,
                                                const float* __restrict__ W4,
                                                float* __restrict__ out,
                                                const float* __restrict__ nbias,
                                                int nmask) {
    int idx = blockIdx.x * TPB + threadIdx.x;   // over 1M, (b,c,p)
    int b = idx >> 18;
    int r = idx & 262143;
    int c = r >> 8, p = r & 255;
    int m = (b << 8) + p;
    size_t pos = (size_t)m * 1024 + c;
    float v = Cm[pos] + W4[idx];
    out[idx] = (v >= 0.0f) ? v : 0.2f * v;
    if (NB) Cm[pos] = nbias[((int)pos) & nmask];
}

// Fused final iwt (12ch -> 3ch, 128->256) + 1x1 conv (3->3, no bias).
__global__ __launch_bounds__(TPB) void final_k(const float* __restrict__ src,
                                               const float* __restrict__ cf,
                                               float* __restrict__ out) {
    int p = blockIdx.x * TPB + threadIdx.x;
    int b = blockIdx.z;
    int h = p >> 7, w = p & 127;
    const int st = 128 * 128;
    float y00[3], y01[3], y10[3], y11[3];
    const float* r = src + (size_t)b * 12 * st + p;
#pragma unroll
    for (int c = 0; c < 3; c++) {
        float v0 = r[(4 * c) * st];
        float v1 = 2.0f * r[(4 * c + 1) * st] - 1.0f;
        float v2 = 2.0f * r[(4 * c + 2) * st] - 1.0f;
        float v3 = 2.0f * r[(4 * c + 3) * st] - 1.0f;
        y00[c] = v0 + 0.5f * ( v1 + v2 + v3);
        y01[c] = v0 + 0.5f * ( v1 - v2 - v3);
        y10[c] = v0 + 0.5f * (-v1 + v2 - v3);
        y11[c] = v0 + 0.5f * (-v1 - v2 + v3);
    }
#pragma unroll
    for (int o = 0; o < 3; o++) {
        float k0 = cf[o * 3], k1 = cf[o * 3 + 1], k2 = cf[o * 3 + 2];
        float* q = out + (((size_t)b * 3 + o) * 256 + 2 * h) * 256 + 2 * w;
        q[0]   = k0 * y00[0] + k1 * y00[1] + k2 * y00[2];
        q[1]   = k0 * y01[0] + k1 * y01[1] + k2 * y01[2];
        q[256] = k0 * y10[0] + k1 * y10[1] + k2 * y10[2];
        q[257] = k0 * y11[0] + k1 * y11[1] + k2 * y11[2];
    }
}

static inline void conv_launch(const float* s0, int C0, const float* s1,
                               const float* wgt, const float* bias,
                               float* out, int Cin, int Cout, int H, int W,
                               int CO, hipStream_t st) {
    dim3 grid((H * W + TPB - 1) / TPB, Cout / CO, 4);
    if (CO == 8)
        conv3x3_k<8, true, false><<<grid, TPB, 0, st>>>(s0, C0, s1, wgt, bias, nullptr, out, Cin, Cout, H, W);
    else
        conv3x3_k<4, true, false><<<grid, TPB, 0, st>>>(s0, C0, s1, wgt, bias, nullptr, out, Cin, Cout, H, W);
}

extern "C" void kernel_launch(void* const* d_in, const int* in_sizes, int n_in,
                              void* d_out, int out_size, void* d_ws, size_t ws_size,
                              hipStream_t stream) {
    (void)in_sizes; (void)n_in; (void)out_size; (void)ws_size;
    const float* x      = (const float*)d_in[0];
    const float* c1w    = (const float*)d_in[1];
    const float* c1b    = (const float*)d_in[2];
    const float* c2w    = (const float*)d_in[3];
    const float* c2b    = (const float*)d_in[4];
    const float* c3w    = (const float*)d_in[5];
    const float* c3b    = (const float*)d_in[6];
    const float* c4w    = (const float*)d_in[7];
    const float* c4b    = (const float*)d_in[8];
    const float* d4w    = (const float*)d_in[9];
    const float* d4b    = (const float*)d_in[10];
    const float* d3w    = (const float*)d_in[11];
    const float* d3b    = (const float*)d_in[12];
    const float* d2w    = (const float*)d_in[13];
    const float* d2b    = (const float*)d_in[14];
    const float* d1w    = (const float*)d_in[15];
    const float* d1b    = (const float*)d_in[16];
    const float* cfin   = (const float*)d_in[17];
    float* out = (float*)d_out;

    char* base = (char*)d_ws;
    const size_t MB = 1 << 20;
    float*    C1   = (float*)(base + 0 * MB);     // (4,16,128,128)
    float*    C3   = (float*)(base + 4 * MB);     // (4,256,32,32)
    float*    W4   = (float*)(base + 8 * MB);     // (4,1024,16,16)
    float*    TA   = (float*)(base + 12 * MB);
    float*    TB   = (float*)(base + 16 * MB);
    float*    C2   = (float*)(base + 20 * MB);    // (4,64,64,64)
    float*    Cmc  = (float*)(base + 24 * MB);    // GEMM acc, 1M floats
    _Float16* X0   = (_Float16*)(base + 28 * MB); // [1024][1024]
    _Float16* X1   = (_Float16*)(base + 30 * MB);
    _Float16* Xa   = (_Float16*)(base + 32 * MB); // w2 [16384][64] / w3 [4096][256]
    _Float16* Xd3  = (_Float16*)(base + 34 * MB); // [16384][128] concat(c2,t3)
    _Float16* Xd4  = (_Float16*)(base + 38 * MB); // [4096][512]  concat(c3,t4)
    _Float16* Bh4  = (_Float16*)(base + 42 * MB); // [1024][9216] 18 MiB
    _Float16* Bh3  = (_Float16*)(base + 60 * MB); // [256][2304]
    _Float16* Bhd4 = (_Float16*)(base + 62 * MB); // [256][4608]
    _Float16* Bhd3 = (_Float16*)(base + 65 * MB); // [64][1152]
    _Float16* Bh2  = (_Float16*)(base + 66 * MB); // [64][576]

    // swizzled weight transforms. n = Cout*9*Cin, KB = 9*Cin/32, grid = n/256.
    wtrans_sw_k<<<36864, TPB, 0, stream>>>(c4w, Bh4, 1024, 288, 9437184);
    wtrans_sw_k<<<2304,  TPB, 0, stream>>>(c3w, Bh3, 256, 72, 589824);
    wtrans_sw_k<<<4608,  TPB, 0, stream>>>(d4w, Bhd4, 512, 144, 1179648);
    wtrans_sw_k<<<288,   TPB, 0, stream>>>(d3w, Bhd3, 128, 36, 73728);
    wtrans_sw_k<<<144,   TPB, 0, stream>>>(c2w, Bh2, 64, 18, 36864);

    // 1. w1 = wt(x): (4,3,256,256) -> (4,12,128,128) spatial, in TA
    wt_k<<<dim3(192, 1, 4), TPB, 0, stream>>>(x, TA, 3, 128, 128);
    // 2. c1 = lrelu(conv1(w1)): 12 -> 16 @128^2 (generic)
    conv_launch(TA, 12, nullptr, c1w, c1b, C1, 12, 16, 128, 128, 8, stream);
    // 3. w2 = wt(c1) -> channels-last Xa [16384][64]
    wt_cl_k<4><<<dim3(256, 1, 4), TPB, 0, stream>>>(C1, Xa, 64, 64);
    // 4. c2 = lrelu(conv2(w2)): GEMM M=16384 N=64 K=576 (KS=3)
    bias_mc_k<<<4096, TPB, 0, stream>>>(Cmc, c2b, 63);
    cgemm_k<6, 2><<<dim3(128, 1, 3), TPB, 0, stream>>>(Xa, Bh2, Cmc, 64, 192, 64);
    fin_cl_k<true, true, true><<<4096, TPB, 0, stream>>>(Cmc, C2, Xd3, 6, 12, 0, 128, c3b, 255);
    // 5. w3 = wt(c2) -> channels-last Xa [4096][256]
    wt_cl_k<6><<<dim3(256, 1, 4), TPB, 0, stream>>>(C2, Xa, 32, 32);
    // 6. c3 = lrelu(conv3(w3)): GEMM M=4096 N=256 K=2304 (KS=8)
    cgemm_k<8, 4><<<dim3(32, 2, 8), TPB, 0, stream>>>(Xa, Bh3, Cmc, 32, 288, 256);
    fin_cl_k<true, true, true><<<4096, TPB, 0, stream>>>(Cmc, C3, Xd4, 8, 10, 0, 512, c4b, 1023);
    // 7. w4 = wt(c3) -> W4 spatial (skip) + X0 channels-last
    wt_dual_k<<<dim3(256, 1, 4), TPB, 0, stream>>>(C3, W4, X0);
    // 8. c4 = lrelu(conv4(w4)) -> X1   (M=N=1024, K=9216, KS=8)
    cgemm_k<10, 4><<<dim3(8, 8, 8), TPB, 0, stream>>>(X0, Bh4, Cmc, 16, 1152, 1024);
    fin_cl_k<false, true, true><<<4096, TPB, 0, stream>>>(Cmc, nullptr, X1, 10, 8, 0, 1024, c4b, 1023);
    // 9. c5 = lrelu(conv4(c4)) -> X0
    cgemm_k<10, 4><<<dim3(8, 8, 8), TPB, 0, stream>>>(X1, Bh4, Cmc, 16, 1152, 1024);
    fin_cl_k<false, true, true><<<4096, TPB, 0, stream>>>(Cmc, nullptr, X0, 10, 8, 0, 1024, c4b, 1023);
    // 10. ic4 = lrelu(conv4(c5) + w4) -> TA spatial; chain d4b
    cgemm_k<10, 4><<<dim3(8, 8, 8), TPB, 0, stream>>>(X0, Bh4, Cmc, 16, 1152, 1024);
    fin_sp_k<true><<<4096, TPB, 0, stream>>>(Cmc, W4, TA, d4b, 255);
    // 11. t4 = iwt(ic4) -> Xd4[:,256:512]
    iwt_cl_k<8><<<dim3(256, 1, 4), TPB, 0, stream>>>(TA, Xd4, 16, 16, 256, 512);
    // 12. ic3 = lrelu(convd4(c3||t4)): GEMM M=4096 N=256 K=4608 (KS=8)
    cgemm_k<9, 4><<<dim3(32, 2, 8), TPB, 0, stream>>>(Xd4, Bhd4, Cmc, 32, 576, 256);
    fin_cl_k<true, false, true><<<4096, TPB, 0, stream>>>(Cmc, TA, nullptr, 8, 10, 0, 0, d3b, 63);
    // 13. t3 = iwt(ic3) -> Xd3[:,64:128]
    iwt_cl_k<6><<<dim3(256, 1, 4), TPB, 0, stream>>>(TA, Xd3, 32, 32, 64, 128);
    // 14. ic2 = lrelu(convd3(c2||t3)): GEMM M=16384 N=64 K=1152 (KS=4)
    cgemm_k<7, 2><<<dim3(128, 1, 4), TPB, 0, stream>>>(Xd3, Bhd3, Cmc, 64, 288, 64);
    fin_cl_k<true, false, false><<<4096, TPB, 0, stream>>>(Cmc, TA, nullptr, 6, 12, 0, 0, nullptr, 0);
    // 15. t2 = iwt(ic2) -> TB spatial (4,16,128,128)
    iwt_k<<<dim3(256, 1, 4), TPB, 0, stream>>>(TA, TB, 16, 64, 64);
    // 16. ic1 = lrelu(convd2(c1||t2)): 32 -> 16 @128^2 (generic) -> TA
    conv_launch(C1, 16, TB, d2w, d2b, TA, 32, 16, 128, 128, 8, stream);
    // 17. iw1 = lrelu(convd1(ic1)): 16 -> 12 @128^2 (generic) -> TB
    conv_launch(TA, 16, TA, d1w, d1b, TB, 16, 12, 128, 128, 4, stream);
    // 18. out = 1x1(iwt(iw1)) fused
    final_k<<<dim3(64, 1, 4), TPB, 0, stream>>>(TB, cfin, out);
}